// Round 3
// baseline (2590.722 us; speedup 1.0000x reference)
//
#include <hip/hip_runtime.h>
#include <hip/hip_bf16.h>

#define N_NODES 100000
#define N_EDGES 1600000
#define IN_DIM 128
#define HID 64
#define N_GRAPHS 64
#define OUT_DIM 2

#define NB_BUCKETS ((N_NODES + 255) / 256)   // 391 buckets of 256 nodes
#define CHUNK 8192
#define NCHUNKS ((N_EDGES + CHUNK - 1) / CHUNK)  // 196

// ---------------- edge bucketing (1-level radix by dst>>8) ----------------

__global__ __launch_bounds__(256) void kb_hist(const int* __restrict__ dst,
                                               int* __restrict__ bcount) {
    __shared__ int hist[NB_BUCKETS];
    int t = threadIdx.x;
    for (int i = t; i < NB_BUCKETS; i += 256) hist[i] = 0;
    __syncthreads();
    int chunk0 = blockIdx.x * CHUNK;
    int cN = min(CHUNK, N_EDGES - chunk0);
    for (int i = t; i < cN; i += 256) atomicAdd(&hist[dst[chunk0 + i] >> 8], 1);
    __syncthreads();
    for (int i = t; i < NB_BUCKETS; i += 256)
        if (hist[i]) atomicAdd(&bcount[i], hist[i]);
}

// exclusive scan of 391 bucket counts (1 block, 1 wave)
__global__ void kb_scan(const int* __restrict__ bcount, int* __restrict__ bbase,
                        int* __restrict__ bcursor) {
    int lane = threadIdx.x;
    int carry = 0;
    for (int c = 0; c < (NB_BUCKETS + 63) / 64; ++c) {
        int idx = c * 64 + lane;
        int v = (idx < NB_BUCKETS) ? bcount[idx] : 0;
        int orig = v;
        for (int d = 1; d < 64; d <<= 1) {
            int u = __shfl_up(v, d);
            if (lane >= d) v += u;
        }
        if (idx < NB_BUCKETS) {
            int ex = v - orig + carry;
            bbase[idx] = ex;
            bcursor[idx] = ex;
        }
        carry += __shfl(v, 63);
    }
    if (lane == 0) bbase[NB_BUCKETS] = carry;
}

// LDS-staged bucket scatter: coalesced global writes (runs ~CHUNK/NB per bucket)
__global__ __launch_bounds__(256) void kb_scatter(const int* __restrict__ src,
                                                  const int* __restrict__ dst,
                                                  int* __restrict__ bcursor,
                                                  unsigned* __restrict__ packed) {
    __shared__ unsigned staged[CHUNK];           // 32 KB
    __shared__ int hist[NB_BUCKETS];
    __shared__ int lofs[NB_BUCKETS + 1];
    __shared__ int lcur[NB_BUCKETS];
    __shared__ int gbase[NB_BUCKETS];
    int t = threadIdx.x;
    int lane = t & 63, wv = t >> 6;
    for (int i = t; i < NB_BUCKETS; i += 256) hist[i] = 0;
    __syncthreads();
    int chunk0 = blockIdx.x * CHUNK;
    int cN = min(CHUNK, N_EDGES - chunk0);
    for (int i = t; i < cN; i += 256) atomicAdd(&hist[dst[chunk0 + i] >> 8], 1);
    __syncthreads();
    if (wv == 0) {  // exclusive scan hist -> lofs
        int carry = 0;
        for (int c = 0; c < (NB_BUCKETS + 63) / 64; ++c) {
            int idx = c * 64 + lane;
            int v = (idx < NB_BUCKETS) ? hist[idx] : 0;
            int orig = v;
            for (int d = 1; d < 64; d <<= 1) {
                int u = __shfl_up(v, d);
                if (lane >= d) v += u;
            }
            if (idx < NB_BUCKETS) lofs[idx] = v - orig + carry;
            carry += __shfl(v, 63);
        }
        if (lane == 0) lofs[NB_BUCKETS] = carry;
    }
    __syncthreads();
    for (int i = t; i < NB_BUCKETS; i += 256) {
        lcur[i] = lofs[i];
        gbase[i] = hist[i] ? atomicAdd(&bcursor[i], hist[i]) : 0;
    }
    __syncthreads();
    for (int i = t; i < cN; i += 256) {  // stage bucket-major in LDS
        int e = chunk0 + i;
        int d = dst[e];
        int b = d >> 8;
        int lp = atomicAdd(&lcur[b], 1);
        staged[lp] = ((unsigned)src[e] << 8) | (unsigned)(d & 255);
    }
    __syncthreads();
    for (int p = t; p < cN; p += 256) {  // coalesced copy-out
        int a = 0, c = NB_BUCKETS;       // find bucket: lofs[a] <= p < lofs[a+1]
        while (c - a > 1) {
            int m = (a + c) >> 1;
            if (lofs[m] <= p) a = m; else c = m;
        }
        packed[gbase[a] + (p - lofs[a])] = staged[p];
    }
}

// per-node degree -> dis, from bucketed edges (no global atomics)
__global__ __launch_bounds__(256) void kb_degdis(const unsigned* __restrict__ packed,
                                                 const int* __restrict__ bbase,
                                                 float* __restrict__ dis) {
    __shared__ int cnt[256];
    int t = threadIdx.x;
    cnt[t] = 0;
    __syncthreads();
    int b = blockIdx.x;
    int lo = bbase[b], hi = bbase[b + 1];
    for (int e = lo + t; e < hi; e += 256) atomicAdd(&cnt[packed[e] & 255], 1);
    __syncthreads();
    int node = b * 256 + t;
    if (node < N_NODES) dis[node] = rsqrtf((float)cnt[t] + 1.0f);  // +1 self-loop
}

// ---------------- conv = scaled GEMM + bucket-aggregate ----------------

// g[i,f] = dis[i] * sum_k A[i,k] * W[k,f]; 64x64 tile, BK=32, 4x4 per thread
template <int K>
__global__ __launch_bounds__(256) void k_gemm(const float* __restrict__ A,
                                              const float* __restrict__ W,
                                              const float* __restrict__ dis,
                                              float* __restrict__ g) {
    __shared__ float As[32][68];
    __shared__ float Ws[32][64];
    int t = threadIdx.x;
    int tx = t & 15, ty = t >> 4;
    int row0 = blockIdx.x * 64;
    float acc[4][4] = {{0.f}};
    int ar = t >> 3;
    int ak = (t & 7) * 4;

    for (int k0 = 0; k0 < K; k0 += 32) {
#pragma unroll
        for (int half = 0; half < 2; ++half) {
            int r = ar + half * 32;
            int grow = row0 + r;
            grow = grow < N_NODES ? grow : N_NODES - 1;
            float4 v = *(const float4*)&A[(size_t)grow * K + k0 + ak];
            As[ak + 0][r] = v.x;
            As[ak + 1][r] = v.y;
            As[ak + 2][r] = v.z;
            As[ak + 3][r] = v.w;
        }
#pragma unroll
        for (int h = 0; h < 2; ++h) {
            int i4 = t + h * 256;
            int kk = i4 >> 4;
            int c4 = (i4 & 15) * 4;
            *(float4*)&Ws[kk][c4] = *(const float4*)&W[(size_t)(k0 + kk) * HID + c4];
        }
        __syncthreads();
#pragma unroll
        for (int kk = 0; kk < 32; ++kk) {
            float4 a = *(const float4*)&As[kk][ty * 4];
            float4 b = *(const float4*)&Ws[kk][tx * 4];
            acc[0][0] = fmaf(a.x, b.x, acc[0][0]);
            acc[0][1] = fmaf(a.x, b.y, acc[0][1]);
            acc[0][2] = fmaf(a.x, b.z, acc[0][2]);
            acc[0][3] = fmaf(a.x, b.w, acc[0][3]);
            acc[1][0] = fmaf(a.y, b.x, acc[1][0]);
            acc[1][1] = fmaf(a.y, b.y, acc[1][1]);
            acc[1][2] = fmaf(a.y, b.z, acc[1][2]);
            acc[1][3] = fmaf(a.y, b.w, acc[1][3]);
            acc[2][0] = fmaf(a.z, b.x, acc[2][0]);
            acc[2][1] = fmaf(a.z, b.y, acc[2][1]);
            acc[2][2] = fmaf(a.z, b.z, acc[2][2]);
            acc[2][3] = fmaf(a.z, b.w, acc[2][3]);
            acc[3][0] = fmaf(a.w, b.x, acc[3][0]);
            acc[3][1] = fmaf(a.w, b.y, acc[3][1]);
            acc[3][2] = fmaf(a.w, b.z, acc[3][2]);
            acc[3][3] = fmaf(a.w, b.w, acc[3][3]);
        }
        __syncthreads();
    }

#pragma unroll
    for (int j = 0; j < 4; ++j) {
        int grow = row0 + ty * 4 + j;
        if (grow < N_NODES) {
            float dr = dis[grow];
            float4 o;
            o.x = acc[j][0] * dr;
            o.y = acc[j][1] * dr;
            o.z = acc[j][2] * dr;
            o.w = acc[j][3] * dr;
            *(float4*)&g[(size_t)grow * HID + tx * 4] = o;
        }
    }
}

// block = bucket of 256 nodes; 64 KB LDS accumulator tile; lane = feature.
// hout[i,:] = act( dis[i]*(sum_{e:dst=i} g[src_e,:] + g[i,:]) + bias )
template <bool RELU>
__global__ __launch_bounds__(256) void k_baggr(const float* __restrict__ g,
                                               const unsigned* __restrict__ packed,
                                               const int* __restrict__ bbase,
                                               const float* __restrict__ dis,
                                               const float* __restrict__ bias,
                                               float* __restrict__ hout) {
    __shared__ float acc[256 * HID];  // 64 KB
    int t = threadIdx.x;
    int lane = t & 63, wv = t >> 6;
    float4* a4 = (float4*)acc;
    for (int i = t; i < 256 * HID / 4; i += 256)
        a4[i] = make_float4(0.f, 0.f, 0.f, 0.f);
    __syncthreads();
    int b = blockIdx.x;
    int lo = bbase[b], hi = bbase[b + 1];
    float bval = bias[lane];
    // 8-deep unrolled edge gather for memory-level parallelism
    for (int e8 = lo + wv * 8; e8 < hi; e8 += 32) {
        int cnt = hi - e8;
        if (cnt > 8) cnt = 8;
        unsigned pkv = 0;
        if (lane < cnt) pkv = packed[e8 + lane];
        float v[8];
        int ld[8];
#pragma unroll
        for (int u = 0; u < 8; ++u) {
            unsigned pk = __shfl(pkv, u);
            ld[u] = (int)(pk & 255u);
            int s = (int)(pk >> 8);
            if (u < cnt) v[u] = g[(size_t)s * HID + lane];
        }
#pragma unroll
        for (int u = 0; u < 8; ++u)
            if (u < cnt) atomicAdd(&acc[ld[u] * HID + lane], v[u]);
    }
    __syncthreads();
    int node0 = b * 256;
    for (int r = wv; r < 256; r += 4) {
        int node = node0 + r;
        if (node < N_NODES) {
            float o = dis[node] * (acc[r * HID + lane] + g[(size_t)node * HID + lane]) + bval;
            if (RELU) o = fmaxf(o, 0.f);
            hout[(size_t)node * HID + lane] = o;
        }
    }
}

// ---------------- pooling + classifier ----------------

__device__ inline int lower_bound_batch(const int* batch, int key) {
    int lo = 0, hi = N_NODES;
    while (lo < hi) {
        int mid = (lo + hi) >> 1;
        if (batch[mid] < key) lo = mid + 1;
        else hi = mid;
    }
    return lo;
}

__global__ void k_pool(const float* __restrict__ h, const int* __restrict__ batch,
                       float* __restrict__ pooled) {
    int gidx = blockIdx.x;
    int lane = threadIdx.x & 63, w = threadIdx.x >> 6;
    __shared__ float sacc[4][HID];
    int lo = lower_bound_batch(batch, gidx);
    int hi = lower_bound_batch(batch, gidx + 1);
    float acc = 0.f;
    for (int i = lo + w; i < hi; i += 4) acc += h[(size_t)i * HID + lane];
    sacc[w][lane] = acc;
    __syncthreads();
    if (w == 0) {
        float s = sacc[0][lane] + sacc[1][lane] + sacc[2][lane] + sacc[3][lane];
        float cntf = (float)(hi - lo);
        pooled[gidx * HID + lane] = s / fmaxf(cntf, 1.0f);
    }
}

__global__ void k_cls(const float* __restrict__ pooled, const float* __restrict__ Wc1,
                      const float* __restrict__ bc1, const float* __restrict__ Wc2,
                      const float* __restrict__ bc2, float* __restrict__ out) {
    __shared__ float hc[N_GRAPHS][HID / 2];
    int t = threadIdx.x;
    for (int idx = t; idx < N_GRAPHS * (HID / 2); idx += blockDim.x) {
        int gi = idx >> 5, f = idx & 31;
        float a = bc1[f];
#pragma unroll
        for (int k = 0; k < HID; ++k) a = fmaf(pooled[gi * HID + k], Wc1[k * (HID / 2) + f], a);
        hc[gi][f] = fmaxf(a, 0.f);
    }
    __syncthreads();
    for (int idx = t; idx < N_GRAPHS * OUT_DIM; idx += blockDim.x) {
        int gi = idx >> 1, f = idx & 1;
        float a = bc2[f];
#pragma unroll
        for (int k = 0; k < HID / 2; ++k) a = fmaf(hc[gi][k], Wc2[k * OUT_DIM + f], a);
        out[gi * OUT_DIM + f] = a;
    }
}

// ---------------- launch ----------------

extern "C" void kernel_launch(void* const* d_in, const int* in_sizes, int n_in,
                              void* d_out, int out_size, void* d_ws, size_t ws_size,
                              hipStream_t stream) {
    const float* x    = (const float*)d_in[0];
    const int*   eidx = (const int*)d_in[1];
    const int*   batch= (const int*)d_in[2];
    const float* W1 = (const float*)d_in[3];  const float* b1 = (const float*)d_in[4];
    const float* W2 = (const float*)d_in[5];  const float* b2 = (const float*)d_in[6];
    const float* W3 = (const float*)d_in[7];  const float* b3 = (const float*)d_in[8];
    const float* Wc1 = (const float*)d_in[9];  const float* bc1 = (const float*)d_in[10];
    const float* Wc2 = (const float*)d_in[11]; const float* bc2 = (const float*)d_in[12];
    float* out = (float*)d_out;

    const int* esrc = eidx;
    const int* edst = eidx + N_EDGES;

    size_t o = 0;
    auto alloc = [&](size_t bytes) {
        void* p = (char*)d_ws + o;
        o += (bytes + 255) & ~(size_t)255;
        return p;
    };
    int*      bcount  = (int*)alloc((size_t)NB_BUCKETS * 4);
    int*      bbase   = (int*)alloc((size_t)(NB_BUCKETS + 1) * 4);
    int*      bcursor = (int*)alloc((size_t)NB_BUCKETS * 4);
    float*    dis     = (float*)alloc((size_t)N_NODES * 4);
    unsigned* packed  = (unsigned*)alloc((size_t)N_EDGES * 4);
    float*    g       = (float*)alloc((size_t)N_NODES * HID * 4);
    float*    hbuf    = (float*)alloc((size_t)N_NODES * HID * 4);
    float*    pooled  = (float*)alloc((size_t)N_GRAPHS * HID * 4);
    (void)ws_size;

    const int TB = 256;
    int gridG = (N_NODES + 63) / 64;

    // 1) bucket edges by dst>>8
    hipMemsetAsync(bcount, 0, (size_t)NB_BUCKETS * 4, stream);
    kb_hist<<<NCHUNKS, TB, 0, stream>>>(edst, bcount);
    kb_scan<<<1, 64, 0, stream>>>(bcount, bbase, bcursor);
    kb_scatter<<<NCHUNKS, TB, 0, stream>>>(esrc, edst, bcursor, packed);
    kb_degdis<<<NB_BUCKETS, TB, 0, stream>>>(packed, bbase, dis);

    // 2) conv1
    k_gemm<IN_DIM><<<gridG, TB, 0, stream>>>(x, W1, dis, g);
    k_baggr<true><<<NB_BUCKETS, TB, 0, stream>>>(g, packed, bbase, dis, b1, hbuf);

    // 3) conv2
    k_gemm<HID><<<gridG, TB, 0, stream>>>(hbuf, W2, dis, g);
    k_baggr<true><<<NB_BUCKETS, TB, 0, stream>>>(g, packed, bbase, dis, b2, hbuf);

    // 4) conv3 (no relu)
    k_gemm<HID><<<gridG, TB, 0, stream>>>(hbuf, W3, dis, g);
    k_baggr<false><<<NB_BUCKETS, TB, 0, stream>>>(g, packed, bbase, dis, b3, hbuf);

    // 5) pool + classifier
    k_pool<<<N_GRAPHS, TB, 0, stream>>>(hbuf, batch, pooled);
    k_cls<<<1, TB, 0, stream>>>(pooled, Wc1, bc1, Wc2, bc2, out);
}

// Round 4
// 539.439 us; speedup vs baseline: 4.8026x; 4.8026x over previous
//
#include <hip/hip_runtime.h>
#include <hip/hip_bf16.h>

#define N_NODES 100000
#define N_EDGES 1600000
#define IN_DIM 128
#define HID 64
#define N_GRAPHS 64
#define OUT_DIM 2

#define NB_BUCKETS ((N_NODES + 255) / 256)   // 391 buckets of 256 nodes
#define CHUNK 8192
#define NCHUNKS ((N_EDGES + CHUNK - 1) / CHUNK)  // 196

// ---------------- edge bucketing (radix by dst>>8, then per-bucket CSR) -----

__global__ __launch_bounds__(256) void kb_hist(const int* __restrict__ dst,
                                               int* __restrict__ bcount) {
    __shared__ int hist[NB_BUCKETS];
    int t = threadIdx.x;
    for (int i = t; i < NB_BUCKETS; i += 256) hist[i] = 0;
    __syncthreads();
    int chunk0 = blockIdx.x * CHUNK;
    int cN = min(CHUNK, N_EDGES - chunk0);
    for (int i = t; i < cN; i += 256) atomicAdd(&hist[dst[chunk0 + i] >> 8], 1);
    __syncthreads();
    for (int i = t; i < NB_BUCKETS; i += 256)
        if (hist[i]) atomicAdd(&bcount[i], hist[i]);
}

// exclusive scan of 391 bucket counts (1 block, 1 wave)
__global__ void kb_scan(const int* __restrict__ bcount, int* __restrict__ bbase,
                        int* __restrict__ bcursor) {
    int lane = threadIdx.x;
    int carry = 0;
    for (int c = 0; c < (NB_BUCKETS + 63) / 64; ++c) {
        int idx = c * 64 + lane;
        int v = (idx < NB_BUCKETS) ? bcount[idx] : 0;
        int orig = v;
        for (int d = 1; d < 64; d <<= 1) {
            int u = __shfl_up(v, d);
            if (lane >= d) v += u;
        }
        if (idx < NB_BUCKETS) {
            int ex = v - orig + carry;
            bbase[idx] = ex;
            bcursor[idx] = ex;
        }
        carry += __shfl(v, 63);
    }
    if (lane == 0) bbase[NB_BUCKETS] = carry;
}

// LDS-staged bucket scatter: coalesced global writes (runs ~CHUNK/NB per bucket)
__global__ __launch_bounds__(256) void kb_scatter(const int* __restrict__ src,
                                                  const int* __restrict__ dst,
                                                  int* __restrict__ bcursor,
                                                  unsigned* __restrict__ packed) {
    __shared__ unsigned staged[CHUNK];           // 32 KB
    __shared__ int hist[NB_BUCKETS];
    __shared__ int lofs[NB_BUCKETS + 1];
    __shared__ int lcur[NB_BUCKETS];
    __shared__ int gbase[NB_BUCKETS];
    int t = threadIdx.x;
    int lane = t & 63, wv = t >> 6;
    for (int i = t; i < NB_BUCKETS; i += 256) hist[i] = 0;
    __syncthreads();
    int chunk0 = blockIdx.x * CHUNK;
    int cN = min(CHUNK, N_EDGES - chunk0);
    for (int i = t; i < cN; i += 256) atomicAdd(&hist[dst[chunk0 + i] >> 8], 1);
    __syncthreads();
    if (wv == 0) {  // exclusive scan hist -> lofs
        int carry = 0;
        for (int c = 0; c < (NB_BUCKETS + 63) / 64; ++c) {
            int idx = c * 64 + lane;
            int v = (idx < NB_BUCKETS) ? hist[idx] : 0;
            int orig = v;
            for (int d = 1; d < 64; d <<= 1) {
                int u = __shfl_up(v, d);
                if (lane >= d) v += u;
            }
            if (idx < NB_BUCKETS) lofs[idx] = v - orig + carry;
            carry += __shfl(v, 63);
        }
        if (lane == 0) lofs[NB_BUCKETS] = carry;
    }
    __syncthreads();
    for (int i = t; i < NB_BUCKETS; i += 256) {
        lcur[i] = lofs[i];
        gbase[i] = hist[i] ? atomicAdd(&bcursor[i], hist[i]) : 0;
    }
    __syncthreads();
    for (int i = t; i < cN; i += 256) {  // stage bucket-major in LDS
        int e = chunk0 + i;
        int d = dst[e];
        int b = d >> 8;
        int lp = atomicAdd(&lcur[b], 1);
        staged[lp] = ((unsigned)src[e] << 8) | (unsigned)(d & 255);
    }
    __syncthreads();
    for (int p = t; p < cN; p += 256) {  // coalesced copy-out
        int a = 0, c = NB_BUCKETS;       // find bucket: lofs[a] <= p < lofs[a+1]
        while (c - a > 1) {
            int m = (a + c) >> 1;
            if (lofs[m] <= p) a = m; else c = m;
        }
        packed[gbase[a] + (p - lofs[a])] = staged[p];
    }
}

// per-bucket finalize: sort bucket into CSR order, write ssrc/off/dis.
// Random writes span only a 16KB window per block -> L2-absorbed.
__global__ __launch_bounds__(256) void k_bfin(const unsigned* __restrict__ packed,
                                              const int* __restrict__ bbase,
                                              int* __restrict__ ssrc,
                                              int* __restrict__ off,
                                              float* __restrict__ dis) {
    __shared__ int cnt[256];
    __shared__ int lofs[256];
    __shared__ int lcur[256];
    int t = threadIdx.x;
    int lane = t & 63, wv = t >> 6;
    cnt[t] = 0;
    __syncthreads();
    int b = blockIdx.x;
    int lo = bbase[b], hi = bbase[b + 1];
    for (int e = lo + t; e < hi; e += 256) atomicAdd(&cnt[packed[e] & 255], 1);
    __syncthreads();
    if (wv == 0) {  // exclusive scan of 256 counts, single wave
        int carry = 0;
#pragma unroll
        for (int c = 0; c < 4; ++c) {
            int idx = c * 64 + lane;
            int v = cnt[idx];
            int orig = v;
            for (int d = 1; d < 64; d <<= 1) {
                int u = __shfl_up(v, d);
                if (lane >= d) v += u;
            }
            lofs[idx] = v - orig + carry;
            carry += __shfl(v, 63);
        }
    }
    __syncthreads();
    lcur[t] = lofs[t];
    int node = b * 256 + t;
    if (node < N_NODES) {
        off[node] = lo + lofs[t];
        dis[node] = rsqrtf((float)cnt[t] + 1.0f);  // +1 = self-loop
    }
    if (b == NB_BUCKETS - 1 && t == 0) off[N_NODES] = N_EDGES;
    __syncthreads();
    for (int e = lo + t; e < hi; e += 256) {
        unsigned pk = packed[e];
        int p = atomicAdd(&lcur[pk & 255u], 1);
        ssrc[lo + p] = (int)(pk >> 8);
    }
}

// ---------------- conv = scaled GEMM + gather-aggregate ----------------

// g[i,f] = dis[i] * sum_k A[i,k] * W[k,f]; 64x64 tile, BK=32, 4x4 per thread
template <int K>
__global__ __launch_bounds__(256) void k_gemm(const float* __restrict__ A,
                                              const float* __restrict__ W,
                                              const float* __restrict__ dis,
                                              float* __restrict__ g) {
    __shared__ float As[32][68];
    __shared__ float Ws[32][64];
    int t = threadIdx.x;
    int tx = t & 15, ty = t >> 4;
    int row0 = blockIdx.x * 64;
    float acc[4][4] = {{0.f}};
    int ar = t >> 3;
    int ak = (t & 7) * 4;

    for (int k0 = 0; k0 < K; k0 += 32) {
#pragma unroll
        for (int half = 0; half < 2; ++half) {
            int r = ar + half * 32;
            int grow = row0 + r;
            grow = grow < N_NODES ? grow : N_NODES - 1;
            float4 v = *(const float4*)&A[(size_t)grow * K + k0 + ak];
            As[ak + 0][r] = v.x;
            As[ak + 1][r] = v.y;
            As[ak + 2][r] = v.z;
            As[ak + 3][r] = v.w;
        }
#pragma unroll
        for (int h = 0; h < 2; ++h) {
            int i4 = t + h * 256;
            int kk = i4 >> 4;
            int c4 = (i4 & 15) * 4;
            *(float4*)&Ws[kk][c4] = *(const float4*)&W[(size_t)(k0 + kk) * HID + c4];
        }
        __syncthreads();
#pragma unroll
        for (int kk = 0; kk < 32; ++kk) {
            float4 a = *(const float4*)&As[kk][ty * 4];
            float4 b = *(const float4*)&Ws[kk][tx * 4];
            acc[0][0] = fmaf(a.x, b.x, acc[0][0]);
            acc[0][1] = fmaf(a.x, b.y, acc[0][1]);
            acc[0][2] = fmaf(a.x, b.z, acc[0][2]);
            acc[0][3] = fmaf(a.x, b.w, acc[0][3]);
            acc[1][0] = fmaf(a.y, b.x, acc[1][0]);
            acc[1][1] = fmaf(a.y, b.y, acc[1][1]);
            acc[1][2] = fmaf(a.y, b.z, acc[1][2]);
            acc[1][3] = fmaf(a.y, b.w, acc[1][3]);
            acc[2][0] = fmaf(a.z, b.x, acc[2][0]);
            acc[2][1] = fmaf(a.z, b.y, acc[2][1]);
            acc[2][2] = fmaf(a.z, b.z, acc[2][2]);
            acc[2][3] = fmaf(a.z, b.w, acc[2][3]);
            acc[3][0] = fmaf(a.w, b.x, acc[3][0]);
            acc[3][1] = fmaf(a.w, b.y, acc[3][1]);
            acc[3][2] = fmaf(a.w, b.z, acc[3][2]);
            acc[3][3] = fmaf(a.w, b.w, acc[3][3]);
        }
        __syncthreads();
    }

#pragma unroll
    for (int j = 0; j < 4; ++j) {
        int grow = row0 + ty * 4 + j;
        if (grow < N_NODES) {
            float dr = dis[grow];
            float4 o;
            o.x = acc[j][0] * dr;
            o.y = acc[j][1] * dr;
            o.z = acc[j][2] * dr;
            o.w = acc[j][3] * dr;
            *(float4*)&g[(size_t)grow * HID + tx * 4] = o;
        }
    }
}

// hout[i,:] = act( dis[i] * (g[i,:] + sum_{e} g[ssrc[e],:]) + b )
// One wave per row; 4 edge slots x 16 lanes x float4, 2-deep unroll (8 gathers in flight).
template <bool RELU>
__global__ __launch_bounds__(256) void k_aggr(const float* __restrict__ g,
                                              const int* __restrict__ off,
                                              const int* __restrict__ ssrc,
                                              const float* __restrict__ dis,
                                              const float* __restrict__ bias,
                                              float* __restrict__ hout) {
    int row = blockIdx.x * 4 + (threadIdx.x >> 6);
    int lane = threadIdx.x & 63;
    int sub = lane >> 4;   // edge slot 0..3
    int li = lane & 15;    // feature float4 index
    if (row >= N_NODES) return;
    const float4* g4 = (const float4*)g;
    float4 acc = make_float4(0.f, 0.f, 0.f, 0.f);
    int lo = off[row], hi = off[row + 1];
    int e = lo + sub;
    for (; e + 4 < hi; e += 8) {  // two edges per slot per iteration
        int s0 = ssrc[e];
        int s1 = ssrc[e + 4];
        float4 v0 = g4[(size_t)s0 * 16 + li];
        float4 v1 = g4[(size_t)s1 * 16 + li];
        acc.x += v0.x + v1.x;
        acc.y += v0.y + v1.y;
        acc.z += v0.z + v1.z;
        acc.w += v0.w + v1.w;
    }
    if (e < hi) {
        int s = ssrc[e];
        float4 v = g4[(size_t)s * 16 + li];
        acc.x += v.x; acc.y += v.y; acc.z += v.z; acc.w += v.w;
    }
#pragma unroll
    for (int d = 16; d <= 32; d <<= 1) {
        acc.x += __shfl_xor(acc.x, d);
        acc.y += __shfl_xor(acc.y, d);
        acc.z += __shfl_xor(acc.z, d);
        acc.w += __shfl_xor(acc.w, d);
    }
    if (sub == 0) {
        float4 self = g4[(size_t)row * 16 + li];
        float dr = dis[row];
        float4 b = ((const float4*)bias)[li];
        float4 o;
        o.x = dr * (acc.x + self.x) + b.x;
        o.y = dr * (acc.y + self.y) + b.y;
        o.z = dr * (acc.z + self.z) + b.z;
        o.w = dr * (acc.w + self.w) + b.w;
        if (RELU) {
            o.x = fmaxf(o.x, 0.f); o.y = fmaxf(o.y, 0.f);
            o.z = fmaxf(o.z, 0.f); o.w = fmaxf(o.w, 0.f);
        }
        ((float4*)hout)[(size_t)row * 16 + li] = o;
    }
}

// ---------------- pooling + classifier ----------------

__device__ inline int lower_bound_batch(const int* batch, int key) {
    int lo = 0, hi = N_NODES;
    while (lo < hi) {
        int mid = (lo + hi) >> 1;
        if (batch[mid] < key) lo = mid + 1;
        else hi = mid;
    }
    return lo;
}

__global__ void k_pool(const float* __restrict__ h, const int* __restrict__ batch,
                       float* __restrict__ pooled) {
    int gidx = blockIdx.x;
    int lane = threadIdx.x & 63, w = threadIdx.x >> 6;
    __shared__ float sacc[4][HID];
    int lo = lower_bound_batch(batch, gidx);
    int hi = lower_bound_batch(batch, gidx + 1);
    float acc = 0.f;
    for (int i = lo + w; i < hi; i += 4) acc += h[(size_t)i * HID + lane];
    sacc[w][lane] = acc;
    __syncthreads();
    if (w == 0) {
        float s = sacc[0][lane] + sacc[1][lane] + sacc[2][lane] + sacc[3][lane];
        float cntf = (float)(hi - lo);
        pooled[gidx * HID + lane] = s / fmaxf(cntf, 1.0f);
    }
}

__global__ void k_cls(const float* __restrict__ pooled, const float* __restrict__ Wc1,
                      const float* __restrict__ bc1, const float* __restrict__ Wc2,
                      const float* __restrict__ bc2, float* __restrict__ out) {
    __shared__ float hc[N_GRAPHS][HID / 2];
    int t = threadIdx.x;
    for (int idx = t; idx < N_GRAPHS * (HID / 2); idx += blockDim.x) {
        int gi = idx >> 5, f = idx & 31;
        float a = bc1[f];
#pragma unroll
        for (int k = 0; k < HID; ++k) a = fmaf(pooled[gi * HID + k], Wc1[k * (HID / 2) + f], a);
        hc[gi][f] = fmaxf(a, 0.f);
    }
    __syncthreads();
    for (int idx = t; idx < N_GRAPHS * OUT_DIM; idx += blockDim.x) {
        int gi = idx >> 1, f = idx & 1;
        float a = bc2[f];
#pragma unroll
        for (int k = 0; k < HID / 2; ++k) a = fmaf(hc[gi][k], Wc2[k * OUT_DIM + f], a);
        out[gi * OUT_DIM + f] = a;
    }
}

// ---------------- launch ----------------

extern "C" void kernel_launch(void* const* d_in, const int* in_sizes, int n_in,
                              void* d_out, int out_size, void* d_ws, size_t ws_size,
                              hipStream_t stream) {
    const float* x    = (const float*)d_in[0];
    const int*   eidx = (const int*)d_in[1];
    const int*   batch= (const int*)d_in[2];
    const float* W1 = (const float*)d_in[3];  const float* b1 = (const float*)d_in[4];
    const float* W2 = (const float*)d_in[5];  const float* b2 = (const float*)d_in[6];
    const float* W3 = (const float*)d_in[7];  const float* b3 = (const float*)d_in[8];
    const float* Wc1 = (const float*)d_in[9];  const float* bc1 = (const float*)d_in[10];
    const float* Wc2 = (const float*)d_in[11]; const float* bc2 = (const float*)d_in[12];
    float* out = (float*)d_out;

    const int* esrc = eidx;
    const int* edst = eidx + N_EDGES;

    size_t o = 0;
    auto alloc = [&](size_t bytes) {
        void* p = (char*)d_ws + o;
        o += (bytes + 255) & ~(size_t)255;
        return p;
    };
    int*      bcount  = (int*)alloc((size_t)NB_BUCKETS * 4);
    int*      bbase   = (int*)alloc((size_t)(NB_BUCKETS + 1) * 4);
    int*      bcursor = (int*)alloc((size_t)NB_BUCKETS * 4);
    float*    dis     = (float*)alloc((size_t)N_NODES * 4);
    unsigned* packed  = (unsigned*)alloc((size_t)N_EDGES * 4);
    int*      ssrc    = (int*)alloc((size_t)N_EDGES * 4);
    int*      off     = (int*)alloc((size_t)(N_NODES + 1) * 4);
    float*    g       = (float*)alloc((size_t)N_NODES * HID * 4);
    float*    hbuf    = (float*)alloc((size_t)N_NODES * HID * 4);
    float*    pooled  = (float*)alloc((size_t)N_GRAPHS * HID * 4);
    (void)ws_size;

    const int TB = 256;
    int gridG = (N_NODES + 63) / 64;
    int gridR = (N_NODES + 3) / 4;

    // 1) bucket edges by dst>>8, then per-bucket CSR finalize (+deg/dis/off)
    hipMemsetAsync(bcount, 0, (size_t)NB_BUCKETS * 4, stream);
    kb_hist<<<NCHUNKS, TB, 0, stream>>>(edst, bcount);
    kb_scan<<<1, 64, 0, stream>>>(bcount, bbase, bcursor);
    kb_scatter<<<NCHUNKS, TB, 0, stream>>>(esrc, edst, bcursor, packed);
    k_bfin<<<NB_BUCKETS, TB, 0, stream>>>(packed, bbase, ssrc, off, dis);

    // 2) conv1
    k_gemm<IN_DIM><<<gridG, TB, 0, stream>>>(x, W1, dis, g);
    k_aggr<true><<<gridR, TB, 0, stream>>>(g, off, ssrc, dis, b1, hbuf);

    // 3) conv2
    k_gemm<HID><<<gridG, TB, 0, stream>>>(hbuf, W2, dis, g);
    k_aggr<true><<<gridR, TB, 0, stream>>>(g, off, ssrc, dis, b2, hbuf);

    // 4) conv3 (no relu)
    k_gemm<HID><<<gridG, TB, 0, stream>>>(hbuf, W3, dis, g);
    k_aggr<false><<<gridR, TB, 0, stream>>>(g, off, ssrc, dis, b3, hbuf);

    // 5) pool + classifier
    k_pool<<<N_GRAPHS, TB, 0, stream>>>(hbuf, batch, pooled);
    k_cls<<<1, TB, 0, stream>>>(pooled, Wc1, bc1, Wc2, bc2, out);
}

// Round 5
// 473.629 us; speedup vs baseline: 5.4699x; 1.1389x over previous
//
#include <hip/hip_runtime.h>
#include <hip/hip_bf16.h>

#define N_NODES 100000
#define N_EDGES 1600000
#define IN_DIM 128
#define HID 64
#define N_GRAPHS 64
#define OUT_DIM 2

#define NB_BUCKETS ((N_NODES + 255) / 256)   // 391 buckets of 256 nodes
#define CHUNK 8192
#define NCHUNKS ((N_EDGES + CHUNK - 1) / CHUNK)  // 196

// ---------------- edge bucketing (radix by dst>>8, then per-bucket CSR) -----

__global__ __launch_bounds__(256) void kb_hist(const int* __restrict__ dst,
                                               int* __restrict__ bcount) {
    __shared__ int hist[NB_BUCKETS];
    int t = threadIdx.x;
    for (int i = t; i < NB_BUCKETS; i += 256) hist[i] = 0;
    __syncthreads();
    int chunk0 = blockIdx.x * CHUNK;
    int cN = min(CHUNK, N_EDGES - chunk0);
    for (int i = t; i < cN; i += 256) atomicAdd(&hist[dst[chunk0 + i] >> 8], 1);
    __syncthreads();
    for (int i = t; i < NB_BUCKETS; i += 256)
        if (hist[i]) atomicAdd(&bcount[i], hist[i]);
}

// exclusive scan of 391 bucket counts (1 block, 1 wave)
__global__ void kb_scan(const int* __restrict__ bcount, int* __restrict__ bbase,
                        int* __restrict__ bcursor) {
    int lane = threadIdx.x;
    int carry = 0;
    for (int c = 0; c < (NB_BUCKETS + 63) / 64; ++c) {
        int idx = c * 64 + lane;
        int v = (idx < NB_BUCKETS) ? bcount[idx] : 0;
        int orig = v;
        for (int d = 1; d < 64; d <<= 1) {
            int u = __shfl_up(v, d);
            if (lane >= d) v += u;
        }
        if (idx < NB_BUCKETS) {
            int ex = v - orig + carry;
            bbase[idx] = ex;
            bcursor[idx] = ex;
        }
        carry += __shfl(v, 63);
    }
    if (lane == 0) bbase[NB_BUCKETS] = carry;
}

// LDS-staged bucket scatter: coalesced global writes (runs ~CHUNK/NB per bucket)
__global__ __launch_bounds__(256) void kb_scatter(const int* __restrict__ src,
                                                  const int* __restrict__ dst,
                                                  int* __restrict__ bcursor,
                                                  unsigned* __restrict__ packed) {
    __shared__ unsigned staged[CHUNK];           // 32 KB
    __shared__ int hist[NB_BUCKETS];
    __shared__ int lofs[NB_BUCKETS + 1];
    __shared__ int lcur[NB_BUCKETS];
    __shared__ int gbase[NB_BUCKETS];
    int t = threadIdx.x;
    int lane = t & 63, wv = t >> 6;
    for (int i = t; i < NB_BUCKETS; i += 256) hist[i] = 0;
    __syncthreads();
    int chunk0 = blockIdx.x * CHUNK;
    int cN = min(CHUNK, N_EDGES - chunk0);
    for (int i = t; i < cN; i += 256) atomicAdd(&hist[dst[chunk0 + i] >> 8], 1);
    __syncthreads();
    if (wv == 0) {  // exclusive scan hist -> lofs
        int carry = 0;
        for (int c = 0; c < (NB_BUCKETS + 63) / 64; ++c) {
            int idx = c * 64 + lane;
            int v = (idx < NB_BUCKETS) ? hist[idx] : 0;
            int orig = v;
            for (int d = 1; d < 64; d <<= 1) {
                int u = __shfl_up(v, d);
                if (lane >= d) v += u;
            }
            if (idx < NB_BUCKETS) lofs[idx] = v - orig + carry;
            carry += __shfl(v, 63);
        }
        if (lane == 0) lofs[NB_BUCKETS] = carry;
    }
    __syncthreads();
    for (int i = t; i < NB_BUCKETS; i += 256) {
        lcur[i] = lofs[i];
        gbase[i] = hist[i] ? atomicAdd(&bcursor[i], hist[i]) : 0;
    }
    __syncthreads();
    for (int i = t; i < cN; i += 256) {  // stage bucket-major in LDS
        int e = chunk0 + i;
        int d = dst[e];
        int b = d >> 8;
        int lp = atomicAdd(&lcur[b], 1);
        staged[lp] = ((unsigned)src[e] << 8) | (unsigned)(d & 255);
    }
    __syncthreads();
    for (int p = t; p < cN; p += 256) {  // coalesced copy-out
        int a = 0, c = NB_BUCKETS;       // find bucket: lofs[a] <= p < lofs[a+1]
        while (c - a > 1) {
            int m = (a + c) >> 1;
            if (lofs[m] <= p) a = m; else c = m;
        }
        packed[gbase[a] + (p - lofs[a])] = staged[p];
    }
}

// per-bucket finalize: sort bucket into CSR order, write ssrc/off/dis.
// Random writes span only a 16KB window per block -> L2-absorbed.
__global__ __launch_bounds__(256) void k_bfin(const unsigned* __restrict__ packed,
                                              const int* __restrict__ bbase,
                                              int* __restrict__ ssrc,
                                              int* __restrict__ off,
                                              float* __restrict__ dis) {
    __shared__ int cnt[256];
    __shared__ int lofs[256];
    __shared__ int lcur[256];
    int t = threadIdx.x;
    int lane = t & 63, wv = t >> 6;
    cnt[t] = 0;
    __syncthreads();
    int b = blockIdx.x;
    int lo = bbase[b], hi = bbase[b + 1];
    for (int e = lo + t; e < hi; e += 256) atomicAdd(&cnt[packed[e] & 255], 1);
    __syncthreads();
    if (wv == 0) {  // exclusive scan of 256 counts, single wave
        int carry = 0;
#pragma unroll
        for (int c = 0; c < 4; ++c) {
            int idx = c * 64 + lane;
            int v = cnt[idx];
            int orig = v;
            for (int d = 1; d < 64; d <<= 1) {
                int u = __shfl_up(v, d);
                if (lane >= d) v += u;
            }
            lofs[idx] = v - orig + carry;
            carry += __shfl(v, 63);
        }
    }
    __syncthreads();
    lcur[t] = lofs[t];
    int node = b * 256 + t;
    if (node < N_NODES) {
        off[node] = lo + lofs[t];
        dis[node] = rsqrtf((float)cnt[t] + 1.0f);  // +1 = self-loop
    }
    if (b == NB_BUCKETS - 1 && t == 0) off[N_NODES] = N_EDGES;
    __syncthreads();
    for (int e = lo + t; e < hi; e += 256) {
        unsigned pk = packed[e];
        int p = atomicAdd(&lcur[pk & 255u], 1);
        ssrc[lo + p] = (int)(pk >> 8);
    }
}

// ---------------- conv = scaled GEMM + gather-aggregate ----------------

// g[i,f] = dis[i] * sum_k A[i,k] * W[k,f]; 64x64 tile, BK=32, 4x4 per thread
template <int K>
__global__ __launch_bounds__(256) void k_gemm(const float* __restrict__ A,
                                              const float* __restrict__ W,
                                              const float* __restrict__ dis,
                                              float* __restrict__ g) {
    __shared__ float As[32][68];
    __shared__ float Ws[32][64];
    int t = threadIdx.x;
    int tx = t & 15, ty = t >> 4;
    int row0 = blockIdx.x * 64;
    float acc[4][4] = {{0.f}};
    int ar = t >> 3;
    int ak = (t & 7) * 4;

    for (int k0 = 0; k0 < K; k0 += 32) {
#pragma unroll
        for (int half = 0; half < 2; ++half) {
            int r = ar + half * 32;
            int grow = row0 + r;
            grow = grow < N_NODES ? grow : N_NODES - 1;
            float4 v = *(const float4*)&A[(size_t)grow * K + k0 + ak];
            As[ak + 0][r] = v.x;
            As[ak + 1][r] = v.y;
            As[ak + 2][r] = v.z;
            As[ak + 3][r] = v.w;
        }
#pragma unroll
        for (int h = 0; h < 2; ++h) {
            int i4 = t + h * 256;
            int kk = i4 >> 4;
            int c4 = (i4 & 15) * 4;
            *(float4*)&Ws[kk][c4] = *(const float4*)&W[(size_t)(k0 + kk) * HID + c4];
        }
        __syncthreads();
#pragma unroll
        for (int kk = 0; kk < 32; ++kk) {
            float4 a = *(const float4*)&As[kk][ty * 4];
            float4 b = *(const float4*)&Ws[kk][tx * 4];
            acc[0][0] = fmaf(a.x, b.x, acc[0][0]);
            acc[0][1] = fmaf(a.x, b.y, acc[0][1]);
            acc[0][2] = fmaf(a.x, b.z, acc[0][2]);
            acc[0][3] = fmaf(a.x, b.w, acc[0][3]);
            acc[1][0] = fmaf(a.y, b.x, acc[1][0]);
            acc[1][1] = fmaf(a.y, b.y, acc[1][1]);
            acc[1][2] = fmaf(a.y, b.z, acc[1][2]);
            acc[1][3] = fmaf(a.y, b.w, acc[1][3]);
            acc[2][0] = fmaf(a.z, b.x, acc[2][0]);
            acc[2][1] = fmaf(a.z, b.y, acc[2][1]);
            acc[2][2] = fmaf(a.z, b.z, acc[2][2]);
            acc[2][3] = fmaf(a.z, b.w, acc[2][3]);
            acc[3][0] = fmaf(a.w, b.x, acc[3][0]);
            acc[3][1] = fmaf(a.w, b.y, acc[3][1]);
            acc[3][2] = fmaf(a.w, b.z, acc[3][2]);
            acc[3][3] = fmaf(a.w, b.w, acc[3][3]);
        }
        __syncthreads();
    }

#pragma unroll
    for (int j = 0; j < 4; ++j) {
        int grow = row0 + ty * 4 + j;
        if (grow < N_NODES) {
            float dr = dis[grow];
            float4 o;
            o.x = acc[j][0] * dr;
            o.y = acc[j][1] * dr;
            o.z = acc[j][2] * dr;
            o.w = acc[j][3] * dr;
            *(float4*)&g[(size_t)grow * HID + tx * 4] = o;
        }
    }
}

// hout[i,:] = act( dis[i] * (g[i,:] + sum_{e} g[ssrc[e],:]) + b )
// One wave per row; 4 edge slots x 16 lanes x float4, 2-deep unroll (8 gathers in flight).
template <bool RELU>
__global__ __launch_bounds__(256) void k_aggr(const float* __restrict__ g,
                                              const int* __restrict__ off,
                                              const int* __restrict__ ssrc,
                                              const float* __restrict__ dis,
                                              const float* __restrict__ bias,
                                              float* __restrict__ hout) {
    int row = blockIdx.x * 4 + (threadIdx.x >> 6);
    int lane = threadIdx.x & 63;
    int sub = lane >> 4;   // edge slot 0..3
    int li = lane & 15;    // feature float4 index
    if (row >= N_NODES) return;
    const float4* g4 = (const float4*)g;
    float4 acc = make_float4(0.f, 0.f, 0.f, 0.f);
    int lo = off[row], hi = off[row + 1];
    int e = lo + sub;
    for (; e + 4 < hi; e += 8) {  // two edges per slot per iteration
        int s0 = ssrc[e];
        int s1 = ssrc[e + 4];
        float4 v0 = g4[(size_t)s0 * 16 + li];
        float4 v1 = g4[(size_t)s1 * 16 + li];
        acc.x += v0.x + v1.x;
        acc.y += v0.y + v1.y;
        acc.z += v0.z + v1.z;
        acc.w += v0.w + v1.w;
    }
    if (e < hi) {
        int s = ssrc[e];
        float4 v = g4[(size_t)s * 16 + li];
        acc.x += v.x; acc.y += v.y; acc.z += v.z; acc.w += v.w;
    }
#pragma unroll
    for (int d = 16; d <= 32; d <<= 1) {
        acc.x += __shfl_xor(acc.x, d);
        acc.y += __shfl_xor(acc.y, d);
        acc.z += __shfl_xor(acc.z, d);
        acc.w += __shfl_xor(acc.w, d);
    }
    if (sub == 0) {
        float4 self = g4[(size_t)row * 16 + li];
        float dr = dis[row];
        float4 b = ((const float4*)bias)[li];
        float4 o;
        o.x = dr * (acc.x + self.x) + b.x;
        o.y = dr * (acc.y + self.y) + b.y;
        o.z = dr * (acc.z + self.z) + b.z;
        o.w = dr * (acc.w + self.w) + b.w;
        if (RELU) {
            o.x = fmaxf(o.x, 0.f); o.y = fmaxf(o.y, 0.f);
            o.z = fmaxf(o.z, 0.f); o.w = fmaxf(o.w, 0.f);
        }
        ((float4*)hout)[(size_t)row * 16 + li] = o;
    }
}

// ---------------- pooling + classifier ----------------

// partial per-graph sums: 391 blocks x 4 waves; each wave covers 64 contiguous
// nodes (batch sorted -> few graph transitions -> few atomic flushes)
__global__ __launch_bounds__(256) void k_pool1(const float* __restrict__ h,
                                               const int* __restrict__ batch,
                                               float* __restrict__ sums) {
    int lane = threadIdx.x & 63, wv = threadIdx.x >> 6;
    int node0 = blockIdx.x * 256 + wv * 64;
    int node1 = min(node0 + 64, N_NODES);
    float acc = 0.f;
    int cur = -1;
    for (int i = node0; i < node1; ++i) {
        int bi = batch[i];
        if (bi != cur) {
            if (cur >= 0) atomicAdd(&sums[cur * HID + lane], acc);
            acc = 0.f;
            cur = bi;
        }
        acc += h[(size_t)i * HID + lane];
    }
    if (cur >= 0) atomicAdd(&sums[cur * HID + lane], acc);
}

__device__ inline int lower_bound_batch(const int* batch, int key) {
    int lo = 0, hi = N_NODES;
    while (lo < hi) {
        int mid = (lo + hi) >> 1;
        if (batch[mid] < key) lo = mid + 1;
        else hi = mid;
    }
    return lo;
}

// finalize (mean) + classifier MLP, single block
__global__ __launch_bounds__(256) void k_cls(const float* __restrict__ sums,
                                             const int* __restrict__ batch,
                                             const float* __restrict__ Wc1,
                                             const float* __restrict__ bc1,
                                             const float* __restrict__ Wc2,
                                             const float* __restrict__ bc2,
                                             float* __restrict__ out) {
    __shared__ float pooled[N_GRAPHS][HID];   // 16 KB
    __shared__ float hc[N_GRAPHS][HID / 2];   // 8 KB
    __shared__ float cnts[N_GRAPHS];
    int t = threadIdx.x;
    if (t < N_GRAPHS) {
        int lo = lower_bound_batch(batch, t);
        int hi = lower_bound_batch(batch, t + 1);
        cnts[t] = fmaxf((float)(hi - lo), 1.0f);
    }
    __syncthreads();
    for (int idx = t; idx < N_GRAPHS * HID; idx += 256) {
        int gi = idx >> 6;
        pooled[gi][idx & 63] = sums[idx] / cnts[gi];
    }
    __syncthreads();
    for (int idx = t; idx < N_GRAPHS * (HID / 2); idx += 256) {
        int gi = idx >> 5, f = idx & 31;
        float a = bc1[f];
#pragma unroll
        for (int k = 0; k < HID; ++k) a = fmaf(pooled[gi][k], Wc1[k * (HID / 2) + f], a);
        hc[gi][f] = fmaxf(a, 0.f);
    }
    __syncthreads();
    for (int idx = t; idx < N_GRAPHS * OUT_DIM; idx += 256) {
        int gi = idx >> 1, f = idx & 1;
        float a = bc2[f];
#pragma unroll
        for (int k = 0; k < HID / 2; ++k) a = fmaf(hc[gi][k], Wc2[k * OUT_DIM + f], a);
        out[gi * OUT_DIM + f] = a;
    }
}

// ---------------- launch ----------------

extern "C" void kernel_launch(void* const* d_in, const int* in_sizes, int n_in,
                              void* d_out, int out_size, void* d_ws, size_t ws_size,
                              hipStream_t stream) {
    const float* x    = (const float*)d_in[0];
    const int*   eidx = (const int*)d_in[1];
    const int*   batch= (const int*)d_in[2];
    const float* W1 = (const float*)d_in[3];  const float* b1 = (const float*)d_in[4];
    const float* W2 = (const float*)d_in[5];  const float* b2 = (const float*)d_in[6];
    const float* W3 = (const float*)d_in[7];  const float* b3 = (const float*)d_in[8];
    const float* Wc1 = (const float*)d_in[9];  const float* bc1 = (const float*)d_in[10];
    const float* Wc2 = (const float*)d_in[11]; const float* bc2 = (const float*)d_in[12];
    float* out = (float*)d_out;

    const int* esrc = eidx;
    const int* edst = eidx + N_EDGES;

    size_t o = 0;
    auto alloc = [&](size_t bytes) {
        void* p = (char*)d_ws + o;
        o += (bytes + 255) & ~(size_t)255;
        return p;
    };
    int*      bcount  = (int*)alloc((size_t)NB_BUCKETS * 4);
    int*      bbase   = (int*)alloc((size_t)(NB_BUCKETS + 1) * 4);
    int*      bcursor = (int*)alloc((size_t)NB_BUCKETS * 4);
    float*    dis     = (float*)alloc((size_t)N_NODES * 4);
    unsigned* packed  = (unsigned*)alloc((size_t)N_EDGES * 4);
    int*      ssrc    = (int*)alloc((size_t)N_EDGES * 4);
    int*      off     = (int*)alloc((size_t)(N_NODES + 1) * 4);
    float*    g       = (float*)alloc((size_t)N_NODES * HID * 4);
    float*    hbuf    = (float*)alloc((size_t)N_NODES * HID * 4);
    float*    sums    = (float*)alloc((size_t)N_GRAPHS * HID * 4);
    (void)ws_size;

    const int TB = 256;
    int gridG = (N_NODES + 63) / 64;
    int gridR = (N_NODES + 3) / 4;

    // 1) bucket edges by dst>>8, then per-bucket CSR finalize (+deg/dis/off)
    hipMemsetAsync(bcount, 0, (size_t)NB_BUCKETS * 4, stream);
    hipMemsetAsync(sums, 0, (size_t)N_GRAPHS * HID * 4, stream);
    kb_hist<<<NCHUNKS, TB, 0, stream>>>(edst, bcount);
    kb_scan<<<1, 64, 0, stream>>>(bcount, bbase, bcursor);
    kb_scatter<<<NCHUNKS, TB, 0, stream>>>(esrc, edst, bcursor, packed);
    k_bfin<<<NB_BUCKETS, TB, 0, stream>>>(packed, bbase, ssrc, off, dis);

    // 2) conv1
    k_gemm<IN_DIM><<<gridG, TB, 0, stream>>>(x, W1, dis, g);
    k_aggr<true><<<gridR, TB, 0, stream>>>(g, off, ssrc, dis, b1, hbuf);

    // 3) conv2
    k_gemm<HID><<<gridG, TB, 0, stream>>>(hbuf, W2, dis, g);
    k_aggr<true><<<gridR, TB, 0, stream>>>(g, off, ssrc, dis, b2, hbuf);

    // 4) conv3 (no relu)
    k_gemm<HID><<<gridG, TB, 0, stream>>>(hbuf, W3, dis, g);
    k_aggr<false><<<gridR, TB, 0, stream>>>(g, off, ssrc, dis, b3, hbuf);

    // 5) pool + classifier
    k_pool1<<<NB_BUCKETS, TB, 0, stream>>>(hbuf, batch, sums);
    k_cls<<<1, TB, 0, stream>>>(sums, batch, Wc1, bc1, Wc2, bc2, out);
}

// Round 6
// 415.946 us; speedup vs baseline: 6.2285x; 1.1387x over previous
//
#include <hip/hip_runtime.h>
#include <hip/hip_bf16.h>

#define N_NODES 100000
#define N_EDGES 1600000
#define IN_DIM 128
#define HID 64
#define N_GRAPHS 64
#define OUT_DIM 2

#define NB_BUCKETS ((N_NODES + 255) / 256)   // 391 buckets of 256 nodes
#define CHUNK 8192
#define NCHUNKS ((N_EDGES + CHUNK - 1) / CHUNK)  // 196

// ---------------- bf16 pack/unpack (RNE) ----------------

__device__ inline unsigned f2bf_rne(float f) {
    unsigned u = __float_as_uint(f);
    u += 0x7FFFu + ((u >> 16) & 1u);
    return u >> 16;
}
__device__ inline unsigned pack2(float lo, float hi) {
    return f2bf_rne(lo) | (f2bf_rne(hi) << 16);
}
__device__ inline float bf_lo(unsigned w) { return __uint_as_float(w << 16); }
__device__ inline float bf_hi(unsigned w) { return __uint_as_float(w & 0xFFFF0000u); }

// ---------------- edge bucketing (radix by dst>>8, then per-bucket CSR) -----

__global__ __launch_bounds__(256) void kb_hist(const int* __restrict__ dst,
                                               int* __restrict__ bcount) {
    __shared__ int hist[NB_BUCKETS];
    int t = threadIdx.x;
    for (int i = t; i < NB_BUCKETS; i += 256) hist[i] = 0;
    __syncthreads();
    int chunk0 = blockIdx.x * CHUNK;
    int cN = min(CHUNK, N_EDGES - chunk0);
    for (int i = t; i < cN; i += 256) atomicAdd(&hist[dst[chunk0 + i] >> 8], 1);
    __syncthreads();
    for (int i = t; i < NB_BUCKETS; i += 256)
        if (hist[i]) atomicAdd(&bcount[i], hist[i]);
}

// exclusive scan of 391 bucket counts (1 block, 1 wave)
__global__ void kb_scan(const int* __restrict__ bcount, int* __restrict__ bbase,
                        int* __restrict__ bcursor) {
    int lane = threadIdx.x;
    int carry = 0;
    for (int c = 0; c < (NB_BUCKETS + 63) / 64; ++c) {
        int idx = c * 64 + lane;
        int v = (idx < NB_BUCKETS) ? bcount[idx] : 0;
        int orig = v;
        for (int d = 1; d < 64; d <<= 1) {
            int u = __shfl_up(v, d);
            if (lane >= d) v += u;
        }
        if (idx < NB_BUCKETS) {
            int ex = v - orig + carry;
            bbase[idx] = ex;
            bcursor[idx] = ex;
        }
        carry += __shfl(v, 63);
    }
    if (lane == 0) bbase[NB_BUCKETS] = carry;
}

// LDS-staged bucket scatter: coalesced global writes
__global__ __launch_bounds__(256) void kb_scatter(const int* __restrict__ src,
                                                  const int* __restrict__ dst,
                                                  int* __restrict__ bcursor,
                                                  unsigned* __restrict__ packed) {
    __shared__ unsigned staged[CHUNK];           // 32 KB
    __shared__ int hist[NB_BUCKETS];
    __shared__ int lofs[NB_BUCKETS + 1];
    __shared__ int lcur[NB_BUCKETS];
    __shared__ int gbase[NB_BUCKETS];
    int t = threadIdx.x;
    int lane = t & 63, wv = t >> 6;
    for (int i = t; i < NB_BUCKETS; i += 256) hist[i] = 0;
    __syncthreads();
    int chunk0 = blockIdx.x * CHUNK;
    int cN = min(CHUNK, N_EDGES - chunk0);
    for (int i = t; i < cN; i += 256) atomicAdd(&hist[dst[chunk0 + i] >> 8], 1);
    __syncthreads();
    if (wv == 0) {
        int carry = 0;
        for (int c = 0; c < (NB_BUCKETS + 63) / 64; ++c) {
            int idx = c * 64 + lane;
            int v = (idx < NB_BUCKETS) ? hist[idx] : 0;
            int orig = v;
            for (int d = 1; d < 64; d <<= 1) {
                int u = __shfl_up(v, d);
                if (lane >= d) v += u;
            }
            if (idx < NB_BUCKETS) lofs[idx] = v - orig + carry;
            carry += __shfl(v, 63);
        }
        if (lane == 0) lofs[NB_BUCKETS] = carry;
    }
    __syncthreads();
    for (int i = t; i < NB_BUCKETS; i += 256) {
        lcur[i] = lofs[i];
        gbase[i] = hist[i] ? atomicAdd(&bcursor[i], hist[i]) : 0;
    }
    __syncthreads();
    for (int i = t; i < cN; i += 256) {
        int e = chunk0 + i;
        int d = dst[e];
        int b = d >> 8;
        int lp = atomicAdd(&lcur[b], 1);
        staged[lp] = ((unsigned)src[e] << 8) | (unsigned)(d & 255);
    }
    __syncthreads();
    for (int p = t; p < cN; p += 256) {
        int a = 0, c = NB_BUCKETS;
        while (c - a > 1) {
            int m = (a + c) >> 1;
            if (lofs[m] <= p) a = m; else c = m;
        }
        packed[gbase[a] + (p - lofs[a])] = staged[p];
    }
}

// per-bucket finalize: sort bucket into CSR order, write ssrc/off/dis.
__global__ __launch_bounds__(256) void k_bfin(const unsigned* __restrict__ packed,
                                              const int* __restrict__ bbase,
                                              int* __restrict__ ssrc,
                                              int* __restrict__ off,
                                              float* __restrict__ dis) {
    __shared__ int cnt[256];
    __shared__ int lofs[256];
    __shared__ int lcur[256];
    int t = threadIdx.x;
    int lane = t & 63, wv = t >> 6;
    cnt[t] = 0;
    __syncthreads();
    int b = blockIdx.x;
    int lo = bbase[b], hi = bbase[b + 1];
    for (int e = lo + t; e < hi; e += 256) atomicAdd(&cnt[packed[e] & 255], 1);
    __syncthreads();
    if (wv == 0) {
        int carry = 0;
#pragma unroll
        for (int c = 0; c < 4; ++c) {
            int idx = c * 64 + lane;
            int v = cnt[idx];
            int orig = v;
            for (int d = 1; d < 64; d <<= 1) {
                int u = __shfl_up(v, d);
                if (lane >= d) v += u;
            }
            lofs[idx] = v - orig + carry;
            carry += __shfl(v, 63);
        }
    }
    __syncthreads();
    lcur[t] = lofs[t];
    int node = b * 256 + t;
    if (node < N_NODES) {
        off[node] = lo + lofs[t];
        dis[node] = rsqrtf((float)cnt[t] + 1.0f);  // +1 = self-loop
    }
    if (b == NB_BUCKETS - 1 && t == 0) off[N_NODES] = N_EDGES;
    __syncthreads();
    for (int e = lo + t; e < hi; e += 256) {
        unsigned pk = packed[e];
        int p = atomicAdd(&lcur[pk & 255u], 1);
        ssrc[lo + p] = (int)(pk >> 8);
    }
}

// ---------------- conv = scaled GEMM (bf16 out) + gather-aggregate ----------

// g16[i,f] = bf16( dis[i] * sum_k A[i,k] * W[k,f] ); 64x64 tile, BK=32
template <int K>
__global__ __launch_bounds__(256) void k_gemm(const float* __restrict__ A,
                                              const float* __restrict__ W,
                                              const float* __restrict__ dis,
                                              unsigned* __restrict__ g16) {
    __shared__ float As[32][68];
    __shared__ float Ws[32][64];
    int t = threadIdx.x;
    int tx = t & 15, ty = t >> 4;
    int row0 = blockIdx.x * 64;
    float acc[4][4] = {{0.f}};
    int ar = t >> 3;
    int ak = (t & 7) * 4;

    for (int k0 = 0; k0 < K; k0 += 32) {
#pragma unroll
        for (int half = 0; half < 2; ++half) {
            int r = ar + half * 32;
            int grow = row0 + r;
            grow = grow < N_NODES ? grow : N_NODES - 1;
            float4 v = *(const float4*)&A[(size_t)grow * K + k0 + ak];
            As[ak + 0][r] = v.x;
            As[ak + 1][r] = v.y;
            As[ak + 2][r] = v.z;
            As[ak + 3][r] = v.w;
        }
#pragma unroll
        for (int h = 0; h < 2; ++h) {
            int i4 = t + h * 256;
            int kk = i4 >> 4;
            int c4 = (i4 & 15) * 4;
            *(float4*)&Ws[kk][c4] = *(const float4*)&W[(size_t)(k0 + kk) * HID + c4];
        }
        __syncthreads();
#pragma unroll
        for (int kk = 0; kk < 32; ++kk) {
            float4 a = *(const float4*)&As[kk][ty * 4];
            float4 b = *(const float4*)&Ws[kk][tx * 4];
            acc[0][0] = fmaf(a.x, b.x, acc[0][0]);
            acc[0][1] = fmaf(a.x, b.y, acc[0][1]);
            acc[0][2] = fmaf(a.x, b.z, acc[0][2]);
            acc[0][3] = fmaf(a.x, b.w, acc[0][3]);
            acc[1][0] = fmaf(a.y, b.x, acc[1][0]);
            acc[1][1] = fmaf(a.y, b.y, acc[1][1]);
            acc[1][2] = fmaf(a.y, b.z, acc[1][2]);
            acc[1][3] = fmaf(a.y, b.w, acc[1][3]);
            acc[2][0] = fmaf(a.z, b.x, acc[2][0]);
            acc[2][1] = fmaf(a.z, b.y, acc[2][1]);
            acc[2][2] = fmaf(a.z, b.z, acc[2][2]);
            acc[2][3] = fmaf(a.z, b.w, acc[2][3]);
            acc[3][0] = fmaf(a.w, b.x, acc[3][0]);
            acc[3][1] = fmaf(a.w, b.y, acc[3][1]);
            acc[3][2] = fmaf(a.w, b.z, acc[3][2]);
            acc[3][3] = fmaf(a.w, b.w, acc[3][3]);
        }
        __syncthreads();
    }

#pragma unroll
    for (int j = 0; j < 4; ++j) {
        int grow = row0 + ty * 4 + j;
        if (grow < N_NODES) {
            float dr = dis[grow];
            uint2 p;
            p.x = pack2(acc[j][0] * dr, acc[j][1] * dr);
            p.y = pack2(acc[j][2] * dr, acc[j][3] * dr);
            // row = 32 uint32 = 16 uint2; thread tx covers pairs [tx*4, tx*4+4)
            ((uint2*)g16)[(size_t)grow * 16 + tx] = p;
        }
    }
}

// hout[i,:] = act( dis[i] * (g16[i,:] + sum_e g16[ssrc[e],:]) + b )   (f32 accum)
// One wave per row; 8 edge slots x 8 lanes x 16B (uint4 = 8 bf16), unroll 2.
template <bool RELU>
__global__ __launch_bounds__(256) void k_aggr(const unsigned* __restrict__ g16,
                                              const int* __restrict__ off,
                                              const int* __restrict__ ssrc,
                                              const float* __restrict__ dis,
                                              const float* __restrict__ bias,
                                              float* __restrict__ hout) {
    int row = blockIdx.x * 4 + (threadIdx.x >> 6);
    int lane = threadIdx.x & 63;
    int sub = lane >> 3;   // edge slot 0..7
    int li = lane & 7;     // 16B segment of the 128B row
    if (row >= N_NODES) return;
    const uint4* g4 = (const uint4*)g16;   // row = 8 uint4
    float acc[8] = {0.f};
    int lo = off[row], hi = off[row + 1];
    int e = lo + sub;
    for (; e + 8 < hi; e += 16) {
        int s0 = ssrc[e];
        int s1 = ssrc[e + 8];
        uint4 v0 = g4[(size_t)s0 * 8 + li];
        uint4 v1 = g4[(size_t)s1 * 8 + li];
        acc[0] += bf_lo(v0.x) + bf_lo(v1.x);
        acc[1] += bf_hi(v0.x) + bf_hi(v1.x);
        acc[2] += bf_lo(v0.y) + bf_lo(v1.y);
        acc[3] += bf_hi(v0.y) + bf_hi(v1.y);
        acc[4] += bf_lo(v0.z) + bf_lo(v1.z);
        acc[5] += bf_hi(v0.z) + bf_hi(v1.z);
        acc[6] += bf_lo(v0.w) + bf_lo(v1.w);
        acc[7] += bf_hi(v0.w) + bf_hi(v1.w);
    }
    if (e < hi) {
        int s = ssrc[e];
        uint4 v = g4[(size_t)s * 8 + li];
        acc[0] += bf_lo(v.x); acc[1] += bf_hi(v.x);
        acc[2] += bf_lo(v.y); acc[3] += bf_hi(v.y);
        acc[4] += bf_lo(v.z); acc[5] += bf_hi(v.z);
        acc[6] += bf_lo(v.w); acc[7] += bf_hi(v.w);
    }
    // combine the 8 edge slots (lanes differing in bits 3..5 hold same features)
#pragma unroll
    for (int d = 8; d <= 32; d <<= 1) {
#pragma unroll
        for (int j = 0; j < 8; ++j) acc[j] += __shfl_xor(acc[j], d);
    }
    if (sub == 0) {
        uint4 sv = g4[(size_t)row * 8 + li];
        float self[8] = {bf_lo(sv.x), bf_hi(sv.x), bf_lo(sv.y), bf_hi(sv.y),
                         bf_lo(sv.z), bf_hi(sv.z), bf_lo(sv.w), bf_hi(sv.w)};
        float dr = dis[row];
        float4 b0 = ((const float4*)bias)[li * 2];
        float4 b1 = ((const float4*)bias)[li * 2 + 1];
        float bb[8] = {b0.x, b0.y, b0.z, b0.w, b1.x, b1.y, b1.z, b1.w};
        float o[8];
#pragma unroll
        for (int j = 0; j < 8; ++j) {
            o[j] = dr * (acc[j] + self[j]) + bb[j];
            if (RELU) o[j] = fmaxf(o[j], 0.f);
        }
        float4* hp = (float4*)&hout[(size_t)row * HID + li * 8];
        hp[0] = make_float4(o[0], o[1], o[2], o[3]);
        hp[1] = make_float4(o[4], o[5], o[6], o[7]);
    }
}

// ---------------- pooling + classifier ----------------

__global__ __launch_bounds__(256) void k_pool1(const float* __restrict__ h,
                                               const int* __restrict__ batch,
                                               float* __restrict__ sums) {
    int lane = threadIdx.x & 63, wv = threadIdx.x >> 6;
    int node0 = blockIdx.x * 256 + wv * 64;
    int node1 = min(node0 + 64, N_NODES);
    float acc = 0.f;
    int cur = -1;
    for (int i = node0; i < node1; ++i) {
        int bi = batch[i];
        if (bi != cur) {
            if (cur >= 0) atomicAdd(&sums[cur * HID + lane], acc);
            acc = 0.f;
            cur = bi;
        }
        acc += h[(size_t)i * HID + lane];
    }
    if (cur >= 0) atomicAdd(&sums[cur * HID + lane], acc);
}

__device__ inline int lower_bound_batch(const int* batch, int key) {
    int lo = 0, hi = N_NODES;
    while (lo < hi) {
        int mid = (lo + hi) >> 1;
        if (batch[mid] < key) lo = mid + 1;
        else hi = mid;
    }
    return lo;
}

__global__ __launch_bounds__(256) void k_cls(const float* __restrict__ sums,
                                             const int* __restrict__ batch,
                                             const float* __restrict__ Wc1,
                                             const float* __restrict__ bc1,
                                             const float* __restrict__ Wc2,
                                             const float* __restrict__ bc2,
                                             float* __restrict__ out) {
    __shared__ float pooled[N_GRAPHS][HID];
    __shared__ float hc[N_GRAPHS][HID / 2];
    __shared__ float cnts[N_GRAPHS];
    int t = threadIdx.x;
    if (t < N_GRAPHS) {
        int lo = lower_bound_batch(batch, t);
        int hi = lower_bound_batch(batch, t + 1);
        cnts[t] = fmaxf((float)(hi - lo), 1.0f);
    }
    __syncthreads();
    for (int idx = t; idx < N_GRAPHS * HID; idx += 256) {
        int gi = idx >> 6;
        pooled[gi][idx & 63] = sums[idx] / cnts[gi];
    }
    __syncthreads();
    for (int idx = t; idx < N_GRAPHS * (HID / 2); idx += 256) {
        int gi = idx >> 5, f = idx & 31;
        float a = bc1[f];
#pragma unroll
        for (int k = 0; k < HID; ++k) a = fmaf(pooled[gi][k], Wc1[k * (HID / 2) + f], a);
        hc[gi][f] = fmaxf(a, 0.f);
    }
    __syncthreads();
    for (int idx = t; idx < N_GRAPHS * OUT_DIM; idx += 256) {
        int gi = idx >> 1, f = idx & 1;
        float a = bc2[f];
#pragma unroll
        for (int k = 0; k < HID / 2; ++k) a = fmaf(hc[gi][k], Wc2[k * OUT_DIM + f], a);
        out[gi * OUT_DIM + f] = a;
    }
}

// ---------------- launch ----------------

extern "C" void kernel_launch(void* const* d_in, const int* in_sizes, int n_in,
                              void* d_out, int out_size, void* d_ws, size_t ws_size,
                              hipStream_t stream) {
    const float* x    = (const float*)d_in[0];
    const int*   eidx = (const int*)d_in[1];
    const int*   batch= (const int*)d_in[2];
    const float* W1 = (const float*)d_in[3];  const float* b1 = (const float*)d_in[4];
    const float* W2 = (const float*)d_in[5];  const float* b2 = (const float*)d_in[6];
    const float* W3 = (const float*)d_in[7];  const float* b3 = (const float*)d_in[8];
    const float* Wc1 = (const float*)d_in[9];  const float* bc1 = (const float*)d_in[10];
    const float* Wc2 = (const float*)d_in[11]; const float* bc2 = (const float*)d_in[12];
    float* out = (float*)d_out;

    const int* esrc = eidx;
    const int* edst = eidx + N_EDGES;

    size_t o = 0;
    auto alloc = [&](size_t bytes) {
        void* p = (char*)d_ws + o;
        o += (bytes + 255) & ~(size_t)255;
        return p;
    };
    int*      bcount  = (int*)alloc((size_t)NB_BUCKETS * 4);
    int*      bbase   = (int*)alloc((size_t)(NB_BUCKETS + 1) * 4);
    int*      bcursor = (int*)alloc((size_t)NB_BUCKETS * 4);
    float*    dis     = (float*)alloc((size_t)N_NODES * 4);
    unsigned* packed  = (unsigned*)alloc((size_t)N_EDGES * 4);
    int*      ssrc    = (int*)alloc((size_t)N_EDGES * 4);
    int*      off     = (int*)alloc((size_t)(N_NODES + 1) * 4);
    unsigned* g16     = (unsigned*)alloc((size_t)N_NODES * HID * 2);  // bf16 rows
    float*    hbuf    = (float*)alloc((size_t)N_NODES * HID * 4);
    float*    sums    = (float*)alloc((size_t)N_GRAPHS * HID * 4);
    (void)ws_size;

    const int TB = 256;
    int gridG = (N_NODES + 63) / 64;
    int gridR = (N_NODES + 3) / 4;

    // 1) bucket edges by dst>>8, then per-bucket CSR finalize (+deg/dis/off)
    hipMemsetAsync(bcount, 0, (size_t)NB_BUCKETS * 4, stream);
    hipMemsetAsync(sums, 0, (size_t)N_GRAPHS * HID * 4, stream);
    kb_hist<<<NCHUNKS, TB, 0, stream>>>(edst, bcount);
    kb_scan<<<1, 64, 0, stream>>>(bcount, bbase, bcursor);
    kb_scatter<<<NCHUNKS, TB, 0, stream>>>(esrc, edst, bcursor, packed);
    k_bfin<<<NB_BUCKETS, TB, 0, stream>>>(packed, bbase, ssrc, off, dis);

    // 2) conv1
    k_gemm<IN_DIM><<<gridG, TB, 0, stream>>>(x, W1, dis, g16);
    k_aggr<true><<<gridR, TB, 0, stream>>>(g16, off, ssrc, dis, b1, hbuf);

    // 3) conv2
    k_gemm<HID><<<gridG, TB, 0, stream>>>(hbuf, W2, dis, g16);
    k_aggr<true><<<gridR, TB, 0, stream>>>(g16, off, ssrc, dis, b2, hbuf);

    // 4) conv3 (no relu)
    k_gemm<HID><<<gridG, TB, 0, stream>>>(hbuf, W3, dis, g16);
    k_aggr<false><<<gridR, TB, 0, stream>>>(g16, off, ssrc, dis, b3, hbuf);

    // 5) pool + classifier
    k_pool1<<<NB_BUCKETS, TB, 0, stream>>>(hbuf, batch, sums);
    k_cls<<<1, TB, 0, stream>>>(sums, batch, Wc1, bc1, Wc2, bc2, out);
}

// Round 7
// 396.820 us; speedup vs baseline: 6.5287x; 1.0482x over previous
//
#include <hip/hip_runtime.h>
#include <hip/hip_bf16.h>

#define N_NODES 100000
#define N_EDGES 1600000
#define IN_DIM 128
#define HID 64
#define N_GRAPHS 64
#define OUT_DIM 2

#define NB_BUCKETS ((N_NODES + 255) / 256)   // 391 buckets of 256 nodes
#define CHUNK 4096
#define NCHUNKS ((N_EDGES + CHUNK - 1) / CHUNK)  // 391

// ---------------- bf16 pack/unpack (RNE) ----------------

__device__ inline unsigned f2bf_rne(float f) {
    unsigned u = __float_as_uint(f);
    u += 0x7FFFu + ((u >> 16) & 1u);
    return u >> 16;
}
__device__ inline unsigned pack2(float lo, float hi) {
    return f2bf_rne(lo) | (f2bf_rne(hi) << 16);
}
__device__ inline float bf_lo(unsigned w) { return __uint_as_float(w << 16); }
__device__ inline float bf_hi(unsigned w) { return __uint_as_float(w & 0xFFFF0000u); }

// ---------------- edge bucketing (radix by dst>>8, then per-bucket CSR) -----

__global__ __launch_bounds__(256) void kb_hist(const int* __restrict__ dst,
                                               int* __restrict__ bcount) {
    __shared__ int hist[NB_BUCKETS];
    int t = threadIdx.x;
    for (int i = t; i < NB_BUCKETS; i += 256) hist[i] = 0;
    __syncthreads();
    int chunk0 = blockIdx.x * CHUNK;
    int cN = min(CHUNK, N_EDGES - chunk0);
    for (int i = t; i < cN; i += 256) atomicAdd(&hist[dst[chunk0 + i] >> 8], 1);
    __syncthreads();
    for (int i = t; i < NB_BUCKETS; i += 256)
        if (hist[i]) atomicAdd(&bcount[i], hist[i]);
}

// exclusive scan of 391 bucket counts (1 block, 1 wave)
__global__ void kb_scan(const int* __restrict__ bcount, int* __restrict__ bbase,
                        int* __restrict__ bcursor) {
    int lane = threadIdx.x;
    int carry = 0;
    for (int c = 0; c < (NB_BUCKETS + 63) / 64; ++c) {
        int idx = c * 64 + lane;
        int v = (idx < NB_BUCKETS) ? bcount[idx] : 0;
        int orig = v;
        for (int d = 1; d < 64; d <<= 1) {
            int u = __shfl_up(v, d);
            if (lane >= d) v += u;
        }
        if (idx < NB_BUCKETS) {
            int ex = v - orig + carry;
            bbase[idx] = ex;
            bcursor[idx] = ex;
        }
        carry += __shfl(v, 63);
    }
    if (lane == 0) bbase[NB_BUCKETS] = carry;
}

// LDS-staged bucket scatter: coalesced global writes, no binary search
// (sbuck[] companion records each staged slot's bucket id)
__global__ __launch_bounds__(256) void kb_scatter(const int* __restrict__ src,
                                                  const int* __restrict__ dst,
                                                  int* __restrict__ bcursor,
                                                  unsigned* __restrict__ packed) {
    __shared__ unsigned staged[CHUNK];            // 16 KB
    __shared__ unsigned short sbuck[CHUNK];       // 8 KB
    __shared__ int hist[NB_BUCKETS];
    __shared__ int lofs[NB_BUCKETS + 1];
    __shared__ int lcur[NB_BUCKETS];
    __shared__ int gbase[NB_BUCKETS];
    int t = threadIdx.x;
    int lane = t & 63, wv = t >> 6;
    for (int i = t; i < NB_BUCKETS; i += 256) hist[i] = 0;
    __syncthreads();
    int chunk0 = blockIdx.x * CHUNK;
    int cN = min(CHUNK, N_EDGES - chunk0);
    for (int i = t; i < cN; i += 256) atomicAdd(&hist[dst[chunk0 + i] >> 8], 1);
    __syncthreads();
    if (wv == 0) {  // exclusive scan hist -> lofs
        int carry = 0;
        for (int c = 0; c < (NB_BUCKETS + 63) / 64; ++c) {
            int idx = c * 64 + lane;
            int v = (idx < NB_BUCKETS) ? hist[idx] : 0;
            int orig = v;
            for (int d = 1; d < 64; d <<= 1) {
                int u = __shfl_up(v, d);
                if (lane >= d) v += u;
            }
            if (idx < NB_BUCKETS) lofs[idx] = v - orig + carry;
            carry += __shfl(v, 63);
        }
        if (lane == 0) lofs[NB_BUCKETS] = carry;
    }
    __syncthreads();
    for (int i = t; i < NB_BUCKETS; i += 256) {
        lcur[i] = lofs[i];
        gbase[i] = hist[i] ? atomicAdd(&bcursor[i], hist[i]) : 0;
    }
    __syncthreads();
    for (int i = t; i < cN; i += 256) {  // stage bucket-major in LDS
        int e = chunk0 + i;
        int d = dst[e];
        int b = d >> 8;
        int lp = atomicAdd(&lcur[b], 1);
        staged[lp] = ((unsigned)src[e] << 8) | (unsigned)(d & 255);
        sbuck[lp] = (unsigned short)b;
    }
    __syncthreads();
    for (int p = t; p < cN; p += 256) {  // coalesced copy-out, direct bucket lookup
        int b = sbuck[p];
        packed[gbase[b] + (p - lofs[b])] = staged[p];
    }
}

// per-bucket finalize: sort bucket into CSR order, write ssrc/off/dis.
__global__ __launch_bounds__(256) void k_bfin(const unsigned* __restrict__ packed,
                                              const int* __restrict__ bbase,
                                              int* __restrict__ ssrc,
                                              int* __restrict__ off,
                                              float* __restrict__ dis) {
    __shared__ int cnt[256];
    __shared__ int lofs[256];
    __shared__ int lcur[256];
    int t = threadIdx.x;
    int lane = t & 63, wv = t >> 6;
    cnt[t] = 0;
    __syncthreads();
    int b = blockIdx.x;
    int lo = bbase[b], hi = bbase[b + 1];
    for (int e = lo + t; e < hi; e += 256) atomicAdd(&cnt[packed[e] & 255], 1);
    __syncthreads();
    if (wv == 0) {
        int carry = 0;
#pragma unroll
        for (int c = 0; c < 4; ++c) {
            int idx = c * 64 + lane;
            int v = cnt[idx];
            int orig = v;
            for (int d = 1; d < 64; d <<= 1) {
                int u = __shfl_up(v, d);
                if (lane >= d) v += u;
            }
            lofs[idx] = v - orig + carry;
            carry += __shfl(v, 63);
        }
    }
    __syncthreads();
    lcur[t] = lofs[t];
    int node = b * 256 + t;
    if (node < N_NODES) {
        off[node] = lo + lofs[t];
        dis[node] = rsqrtf((float)cnt[t] + 1.0f);  // +1 = self-loop
    }
    if (b == NB_BUCKETS - 1 && t == 0) off[N_NODES] = N_EDGES;
    __syncthreads();
    for (int e = lo + t; e < hi; e += 256) {
        unsigned pk = packed[e];
        int p = atomicAdd(&lcur[pk & 255u], 1);
        ssrc[lo + p] = (int)(pk >> 8);
    }
}

// ---------------- conv = scaled GEMM (bf16 out) + gather-aggregate ----------

// g16[i,f] = bf16( dis[i] * sum_k A[i,k] * W[k,f] ); 64x64 tile, BK=32
template <int K>
__global__ __launch_bounds__(256) void k_gemm(const float* __restrict__ A,
                                              const float* __restrict__ W,
                                              const float* __restrict__ dis,
                                              unsigned* __restrict__ g16) {
    __shared__ float As[32][68];
    __shared__ float Ws[32][64];
    int t = threadIdx.x;
    int tx = t & 15, ty = t >> 4;
    int row0 = blockIdx.x * 64;
    float acc[4][4] = {{0.f}};
    int ar = t >> 3;
    int ak = (t & 7) * 4;

    for (int k0 = 0; k0 < K; k0 += 32) {
#pragma unroll
        for (int half = 0; half < 2; ++half) {
            int r = ar + half * 32;
            int grow = row0 + r;
            grow = grow < N_NODES ? grow : N_NODES - 1;
            float4 v = *(const float4*)&A[(size_t)grow * K + k0 + ak];
            As[ak + 0][r] = v.x;
            As[ak + 1][r] = v.y;
            As[ak + 2][r] = v.z;
            As[ak + 3][r] = v.w;
        }
#pragma unroll
        for (int h = 0; h < 2; ++h) {
            int i4 = t + h * 256;
            int kk = i4 >> 4;
            int c4 = (i4 & 15) * 4;
            *(float4*)&Ws[kk][c4] = *(const float4*)&W[(size_t)(k0 + kk) * HID + c4];
        }
        __syncthreads();
#pragma unroll
        for (int kk = 0; kk < 32; ++kk) {
            float4 a = *(const float4*)&As[kk][ty * 4];
            float4 b = *(const float4*)&Ws[kk][tx * 4];
            acc[0][0] = fmaf(a.x, b.x, acc[0][0]);
            acc[0][1] = fmaf(a.x, b.y, acc[0][1]);
            acc[0][2] = fmaf(a.x, b.z, acc[0][2]);
            acc[0][3] = fmaf(a.x, b.w, acc[0][3]);
            acc[1][0] = fmaf(a.y, b.x, acc[1][0]);
            acc[1][1] = fmaf(a.y, b.y, acc[1][1]);
            acc[1][2] = fmaf(a.y, b.z, acc[1][2]);
            acc[1][3] = fmaf(a.y, b.w, acc[1][3]);
            acc[2][0] = fmaf(a.z, b.x, acc[2][0]);
            acc[2][1] = fmaf(a.z, b.y, acc[2][1]);
            acc[2][2] = fmaf(a.z, b.z, acc[2][2]);
            acc[2][3] = fmaf(a.z, b.w, acc[2][3]);
            acc[3][0] = fmaf(a.w, b.x, acc[3][0]);
            acc[3][1] = fmaf(a.w, b.y, acc[3][1]);
            acc[3][2] = fmaf(a.w, b.z, acc[3][2]);
            acc[3][3] = fmaf(a.w, b.w, acc[3][3]);
        }
        __syncthreads();
    }

#pragma unroll
    for (int j = 0; j < 4; ++j) {
        int grow = row0 + ty * 4 + j;
        if (grow < N_NODES) {
            float dr = dis[grow];
            uint2 p;
            p.x = pack2(acc[j][0] * dr, acc[j][1] * dr);
            p.y = pack2(acc[j][2] * dr, acc[j][3] * dr);
            ((uint2*)g16)[(size_t)grow * 16 + tx] = p;
        }
    }
}

// hout[i,:] = act( dis[i] * (g16[i,:] + sum_e g16[ssrc[e],:]) + b )   (f32 accum)
// One wave per row; 8 edge slots x 8 lanes x 16B (uint4 = 8 bf16), unroll 2.
template <bool RELU>
__global__ __launch_bounds__(256) void k_aggr(const unsigned* __restrict__ g16,
                                              const int* __restrict__ off,
                                              const int* __restrict__ ssrc,
                                              const float* __restrict__ dis,
                                              const float* __restrict__ bias,
                                              float* __restrict__ hout) {
    int row = blockIdx.x * 4 + (threadIdx.x >> 6);
    int lane = threadIdx.x & 63;
    int sub = lane >> 3;   // edge slot 0..7
    int li = lane & 7;     // 16B segment of the 128B row
    if (row >= N_NODES) return;
    const uint4* g4 = (const uint4*)g16;   // row = 8 uint4
    float acc[8] = {0.f};
    int lo = off[row], hi = off[row + 1];
    int e = lo + sub;
    for (; e + 8 < hi; e += 16) {
        int s0 = ssrc[e];
        int s1 = ssrc[e + 8];
        uint4 v0 = g4[(size_t)s0 * 8 + li];
        uint4 v1 = g4[(size_t)s1 * 8 + li];
        acc[0] += bf_lo(v0.x) + bf_lo(v1.x);
        acc[1] += bf_hi(v0.x) + bf_hi(v1.x);
        acc[2] += bf_lo(v0.y) + bf_lo(v1.y);
        acc[3] += bf_hi(v0.y) + bf_hi(v1.y);
        acc[4] += bf_lo(v0.z) + bf_lo(v1.z);
        acc[5] += bf_hi(v0.z) + bf_hi(v1.z);
        acc[6] += bf_lo(v0.w) + bf_lo(v1.w);
        acc[7] += bf_hi(v0.w) + bf_hi(v1.w);
    }
    if (e < hi) {
        int s = ssrc[e];
        uint4 v = g4[(size_t)s * 8 + li];
        acc[0] += bf_lo(v.x); acc[1] += bf_hi(v.x);
        acc[2] += bf_lo(v.y); acc[3] += bf_hi(v.y);
        acc[4] += bf_lo(v.z); acc[5] += bf_hi(v.z);
        acc[6] += bf_lo(v.w); acc[7] += bf_hi(v.w);
    }
#pragma unroll
    for (int d = 8; d <= 32; d <<= 1) {
#pragma unroll
        for (int j = 0; j < 8; ++j) acc[j] += __shfl_xor(acc[j], d);
    }
    if (sub == 0) {
        uint4 sv = g4[(size_t)row * 8 + li];
        float self[8] = {bf_lo(sv.x), bf_hi(sv.x), bf_lo(sv.y), bf_hi(sv.y),
                         bf_lo(sv.z), bf_hi(sv.z), bf_lo(sv.w), bf_hi(sv.w)};
        float dr = dis[row];
        float4 b0 = ((const float4*)bias)[li * 2];
        float4 b1 = ((const float4*)bias)[li * 2 + 1];
        float bb[8] = {b0.x, b0.y, b0.z, b0.w, b1.x, b1.y, b1.z, b1.w};
        float o[8];
#pragma unroll
        for (int j = 0; j < 8; ++j) {
            o[j] = dr * (acc[j] + self[j]) + bb[j];
            if (RELU) o[j] = fmaxf(o[j], 0.f);
        }
        float4* hp = (float4*)&hout[(size_t)row * HID + li * 8];
        hp[0] = make_float4(o[0], o[1], o[2], o[3]);
        hp[1] = make_float4(o[4], o[5], o[6], o[7]);
    }
}

// ---------------- pooling + classifier ----------------

__global__ __launch_bounds__(256) void k_pool1(const float* __restrict__ h,
                                               const int* __restrict__ batch,
                                               float* __restrict__ sums) {
    int lane = threadIdx.x & 63, wv = threadIdx.x >> 6;
    int node0 = blockIdx.x * 256 + wv * 64;
    int node1 = min(node0 + 64, N_NODES);
    float acc = 0.f;
    int cur = -1;
    for (int i = node0; i < node1; ++i) {
        int bi = batch[i];
        if (bi != cur) {
            if (cur >= 0) atomicAdd(&sums[cur * HID + lane], acc);
            acc = 0.f;
            cur = bi;
        }
        acc += h[(size_t)i * HID + lane];
    }
    if (cur >= 0) atomicAdd(&sums[cur * HID + lane], acc);
}

__device__ inline int lower_bound_batch(const int* batch, int key) {
    int lo = 0, hi = N_NODES;
    while (lo < hi) {
        int mid = (lo + hi) >> 1;
        if (batch[mid] < key) lo = mid + 1;
        else hi = mid;
    }
    return lo;
}

__global__ __launch_bounds__(256) void k_cls(const float* __restrict__ sums,
                                             const int* __restrict__ batch,
                                             const float* __restrict__ Wc1,
                                             const float* __restrict__ bc1,
                                             const float* __restrict__ Wc2,
                                             const float* __restrict__ bc2,
                                             float* __restrict__ out) {
    __shared__ float pooled[N_GRAPHS][HID];
    __shared__ float hc[N_GRAPHS][HID / 2];
    __shared__ float cnts[N_GRAPHS];
    int t = threadIdx.x;
    if (t < N_GRAPHS) {
        int lo = lower_bound_batch(batch, t);
        int hi = lower_bound_batch(batch, t + 1);
        cnts[t] = fmaxf((float)(hi - lo), 1.0f);
    }
    __syncthreads();
    for (int idx = t; idx < N_GRAPHS * HID; idx += 256) {
        int gi = idx >> 6;
        pooled[gi][idx & 63] = sums[idx] / cnts[gi];
    }
    __syncthreads();
    for (int idx = t; idx < N_GRAPHS * (HID / 2); idx += 256) {
        int gi = idx >> 5, f = idx & 31;
        float a = bc1[f];
#pragma unroll
        for (int k = 0; k < HID; ++k) a = fmaf(pooled[gi][k], Wc1[k * (HID / 2) + f], a);
        hc[gi][f] = fmaxf(a, 0.f);
    }
    __syncthreads();
    for (int idx = t; idx < N_GRAPHS * OUT_DIM; idx += 256) {
        int gi = idx >> 1, f = idx & 1;
        float a = bc2[f];
#pragma unroll
        for (int k = 0; k < HID / 2; ++k) a = fmaf(hc[gi][k], Wc2[k * OUT_DIM + f], a);
        out[gi * OUT_DIM + f] = a;
    }
}

// ---------------- launch ----------------

extern "C" void kernel_launch(void* const* d_in, const int* in_sizes, int n_in,
                              void* d_out, int out_size, void* d_ws, size_t ws_size,
                              hipStream_t stream) {
    const float* x    = (const float*)d_in[0];
    const int*   eidx = (const int*)d_in[1];
    const int*   batch= (const int*)d_in[2];
    const float* W1 = (const float*)d_in[3];  const float* b1 = (const float*)d_in[4];
    const float* W2 = (const float*)d_in[5];  const float* b2 = (const float*)d_in[6];
    const float* W3 = (const float*)d_in[7];  const float* b3 = (const float*)d_in[8];
    const float* Wc1 = (const float*)d_in[9];  const float* bc1 = (const float*)d_in[10];
    const float* Wc2 = (const float*)d_in[11]; const float* bc2 = (const float*)d_in[12];
    float* out = (float*)d_out;

    const int* esrc = eidx;
    const int* edst = eidx + N_EDGES;

    size_t o = 0;
    auto alloc = [&](size_t bytes) {
        void* p = (char*)d_ws + o;
        o += (bytes + 255) & ~(size_t)255;
        return p;
    };
    int*      bcount  = (int*)alloc((size_t)NB_BUCKETS * 4);
    int*      bbase   = (int*)alloc((size_t)(NB_BUCKETS + 1) * 4);
    int*      bcursor = (int*)alloc((size_t)NB_BUCKETS * 4);
    float*    dis     = (float*)alloc((size_t)N_NODES * 4);
    unsigned* packed  = (unsigned*)alloc((size_t)N_EDGES * 4);
    int*      ssrc    = (int*)alloc((size_t)N_EDGES * 4);
    int*      off     = (int*)alloc((size_t)(N_NODES + 1) * 4);
    unsigned* g16     = (unsigned*)alloc((size_t)N_NODES * HID * 2);  // bf16 rows
    float*    hbuf    = (float*)alloc((size_t)N_NODES * HID * 4);
    float*    sums    = (float*)alloc((size_t)N_GRAPHS * HID * 4);
    (void)ws_size;

    const int TB = 256;
    int gridG = (N_NODES + 63) / 64;
    int gridR = (N_NODES + 3) / 4;

    // 1) bucket edges by dst>>8, then per-bucket CSR finalize (+deg/dis/off)
    hipMemsetAsync(bcount, 0, (size_t)NB_BUCKETS * 4, stream);
    hipMemsetAsync(sums, 0, (size_t)N_GRAPHS * HID * 4, stream);
    kb_hist<<<NCHUNKS, TB, 0, stream>>>(edst, bcount);
    kb_scan<<<1, 64, 0, stream>>>(bcount, bbase, bcursor);
    kb_scatter<<<NCHUNKS, TB, 0, stream>>>(esrc, edst, bcursor, packed);
    k_bfin<<<NB_BUCKETS, TB, 0, stream>>>(packed, bbase, ssrc, off, dis);

    // 2) conv1
    k_gemm<IN_DIM><<<gridG, TB, 0, stream>>>(x, W1, dis, g16);
    k_aggr<true><<<gridR, TB, 0, stream>>>(g16, off, ssrc, dis, b1, hbuf);

    // 3) conv2
    k_gemm<HID><<<gridG, TB, 0, stream>>>(hbuf, W2, dis, g16);
    k_aggr<true><<<gridR, TB, 0, stream>>>(g16, off, ssrc, dis, b2, hbuf);

    // 4) conv3 (no relu)
    k_gemm<HID><<<gridG, TB, 0, stream>>>(hbuf, W3, dis, g16);
    k_aggr<false><<<gridR, TB, 0, stream>>>(g16, off, ssrc, dis, b3, hbuf);

    // 5) pool + classifier
    k_pool1<<<NB_BUCKETS, TB, 0, stream>>>(hbuf, batch, sums);
    k_cls<<<1, TB, 0, stream>>>(sums, batch, Wc1, bc1, Wc2, bc2, out);
}

// Round 8
// 388.753 us; speedup vs baseline: 6.6642x; 1.0208x over previous
//
#include <hip/hip_runtime.h>
#include <hip/hip_bf16.h>

#define N_NODES 100000
#define N_EDGES 1600000
#define IN_DIM 128
#define HID 64
#define N_GRAPHS 64
#define OUT_DIM 2

#define NB_BUCKETS ((N_NODES + 255) / 256)   // 391 buckets of 256 nodes
#define CHUNK 4096
#define NCHUNKS ((N_EDGES + CHUNK - 1) / CHUNK)  // 391
#define ARENA_CAP 6144   // per-bucket arena slots; mean 4092, sigma 64 -> +32 sigma

// ---------------- bf16 pack/unpack (RNE) ----------------

__device__ inline unsigned f2bf_rne(float f) {
    unsigned u = __float_as_uint(f);
    u += 0x7FFFu + ((u >> 16) & 1u);
    return u >> 16;
}
__device__ inline unsigned pack2(float lo, float hi) {
    return f2bf_rne(lo) | (f2bf_rne(hi) << 16);
}
__device__ inline float bf_lo(unsigned w) { return __uint_as_float(w << 16); }
__device__ inline float bf_hi(unsigned w) { return __uint_as_float(w & 0xFFFF0000u); }
__device__ inline float2 bf_pair(unsigned w) {
    return make_float2(bf_lo(w), bf_hi(w));
}
__device__ inline void acc2(float2& a, float2 b) { a.x += b.x; a.y += b.y; }

// ---------------- edge bucketing (single-pass arena scatter) ----------------

// exclusive scan of 391 bucket counts (1 block, 1 wave)
__global__ void kb_scan(const int* __restrict__ bcount, int* __restrict__ bbase) {
    int lane = threadIdx.x;
    int carry = 0;
    for (int c = 0; c < (NB_BUCKETS + 63) / 64; ++c) {
        int idx = c * 64 + lane;
        int v = (idx < NB_BUCKETS) ? bcount[idx] : 0;
        int orig = v;
        for (int d = 1; d < 64; d <<= 1) {
            int u = __shfl_up(v, d);
            if (lane >= d) v += u;
        }
        if (idx < NB_BUCKETS) bbase[idx] = v - orig + carry;
        carry += __shfl(v, 63);
    }
    if (lane == 0) bbase[NB_BUCKETS] = carry;
}

// LDS-staged bucket scatter into fixed-capacity arena; reserves space via
// atomicAdd on bcount (which afterwards holds the true per-bucket counts).
__global__ __launch_bounds__(256) void kb_scatter(const int* __restrict__ src,
                                                  const int* __restrict__ dst,
                                                  int* __restrict__ bcount,
                                                  unsigned* __restrict__ arena) {
    __shared__ unsigned staged[CHUNK];            // 16 KB
    __shared__ unsigned short sbuck[CHUNK];       // 8 KB
    __shared__ int hist[NB_BUCKETS];
    __shared__ int lofs[NB_BUCKETS];
    __shared__ int lcur[NB_BUCKETS];
    __shared__ int gbase[NB_BUCKETS];
    int t = threadIdx.x;
    int lane = t & 63, wv = t >> 6;
    for (int i = t; i < NB_BUCKETS; i += 256) hist[i] = 0;
    __syncthreads();
    int chunk0 = blockIdx.x * CHUNK;
    int cN = min(CHUNK, N_EDGES - chunk0);
    for (int i = t; i < cN; i += 256) atomicAdd(&hist[dst[chunk0 + i] >> 8], 1);
    __syncthreads();
    if (wv == 0) {  // exclusive scan hist -> lofs
        int carry = 0;
        for (int c = 0; c < (NB_BUCKETS + 63) / 64; ++c) {
            int idx = c * 64 + lane;
            int v = (idx < NB_BUCKETS) ? hist[idx] : 0;
            int orig = v;
            for (int d = 1; d < 64; d <<= 1) {
                int u = __shfl_up(v, d);
                if (lane >= d) v += u;
            }
            if (idx < NB_BUCKETS) lofs[idx] = v - orig + carry;
            carry += __shfl(v, 63);
        }
    }
    __syncthreads();
    for (int i = t; i < NB_BUCKETS; i += 256) {
        lcur[i] = lofs[i];
        gbase[i] = hist[i] ? (atomicAdd(&bcount[i], hist[i]) + i * ARENA_CAP) : 0;
    }
    __syncthreads();
    for (int i = t; i < cN; i += 256) {  // stage bucket-major in LDS
        int e = chunk0 + i;
        int d = dst[e];
        int b = d >> 8;
        int lp = atomicAdd(&lcur[b], 1);
        staged[lp] = ((unsigned)src[e] << 8) | (unsigned)(d & 255);
        sbuck[lp] = (unsigned short)b;
    }
    __syncthreads();
    for (int p = t; p < cN; p += 256) {  // coalesced copy-out, direct bucket lookup
        int b = sbuck[p];
        arena[gbase[b] + (p - lofs[b])] = staged[p];
    }
}

// per-bucket finalize: sort bucket into CSR order, write ssrc/off/dis.
__global__ __launch_bounds__(256) void k_bfin(const unsigned* __restrict__ arena,
                                              const int* __restrict__ bbase,
                                              int* __restrict__ ssrc,
                                              int* __restrict__ off,
                                              float* __restrict__ dis) {
    __shared__ int cnt[256];
    __shared__ int lofs[256];
    __shared__ int lcur[256];
    int t = threadIdx.x;
    int lane = t & 63, wv = t >> 6;
    cnt[t] = 0;
    __syncthreads();
    int b = blockIdx.x;
    int lo = bbase[b];
    int cntB = bbase[b + 1] - lo;
    const unsigned* ap = arena + (size_t)b * ARENA_CAP;
    for (int e = t; e < cntB; e += 256) atomicAdd(&cnt[ap[e] & 255], 1);
    __syncthreads();
    if (wv == 0) {  // exclusive scan of 256 counts, single wave
        int carry = 0;
#pragma unroll
        for (int c = 0; c < 4; ++c) {
            int idx = c * 64 + lane;
            int v = cnt[idx];
            int orig = v;
            for (int d = 1; d < 64; d <<= 1) {
                int u = __shfl_up(v, d);
                if (lane >= d) v += u;
            }
            lofs[idx] = v - orig + carry;
            carry += __shfl(v, 63);
        }
    }
    __syncthreads();
    lcur[t] = lofs[t];
    int node = b * 256 + t;
    if (node < N_NODES) {
        off[node] = lo + lofs[t];
        dis[node] = rsqrtf((float)cnt[t] + 1.0f);  // +1 = self-loop
    }
    if (b == NB_BUCKETS - 1 && t == 0) off[N_NODES] = N_EDGES;
    __syncthreads();
    for (int e = t; e < cntB; e += 256) {
        unsigned pk = ap[e];
        int p = atomicAdd(&lcur[pk & 255u], 1);
        ssrc[lo + p] = (int)(pk >> 8);
    }
}

// ---------------- conv = scaled GEMM (bf16 out) + gather-aggregate ----------

// g16[i,f] = bf16( dis[i] * sum_k A[i,k] * W[k,f] ); 64x64 tile, BK=32
template <int K>
__global__ __launch_bounds__(256) void k_gemm(const float* __restrict__ A,
                                              const float* __restrict__ W,
                                              const float* __restrict__ dis,
                                              unsigned* __restrict__ g16) {
    __shared__ float As[32][68];
    __shared__ float Ws[32][64];
    int t = threadIdx.x;
    int tx = t & 15, ty = t >> 4;
    int row0 = blockIdx.x * 64;
    float acc[4][4] = {{0.f}};
    int ar = t >> 3;
    int ak = (t & 7) * 4;

    for (int k0 = 0; k0 < K; k0 += 32) {
#pragma unroll
        for (int half = 0; half < 2; ++half) {
            int r = ar + half * 32;
            int grow = row0 + r;
            grow = grow < N_NODES ? grow : N_NODES - 1;
            float4 v = *(const float4*)&A[(size_t)grow * K + k0 + ak];
            As[ak + 0][r] = v.x;
            As[ak + 1][r] = v.y;
            As[ak + 2][r] = v.z;
            As[ak + 3][r] = v.w;
        }
#pragma unroll
        for (int h = 0; h < 2; ++h) {
            int i4 = t + h * 256;
            int kk = i4 >> 4;
            int c4 = (i4 & 15) * 4;
            *(float4*)&Ws[kk][c4] = *(const float4*)&W[(size_t)(k0 + kk) * HID + c4];
        }
        __syncthreads();
#pragma unroll
        for (int kk = 0; kk < 32; ++kk) {
            float4 a = *(const float4*)&As[kk][ty * 4];
            float4 b = *(const float4*)&Ws[kk][tx * 4];
            acc[0][0] = fmaf(a.x, b.x, acc[0][0]);
            acc[0][1] = fmaf(a.x, b.y, acc[0][1]);
            acc[0][2] = fmaf(a.x, b.z, acc[0][2]);
            acc[0][3] = fmaf(a.x, b.w, acc[0][3]);
            acc[1][0] = fmaf(a.y, b.x, acc[1][0]);
            acc[1][1] = fmaf(a.y, b.y, acc[1][1]);
            acc[1][2] = fmaf(a.y, b.z, acc[1][2]);
            acc[1][3] = fmaf(a.y, b.w, acc[1][3]);
            acc[2][0] = fmaf(a.z, b.x, acc[2][0]);
            acc[2][1] = fmaf(a.z, b.y, acc[2][1]);
            acc[2][2] = fmaf(a.z, b.z, acc[2][2]);
            acc[2][3] = fmaf(a.z, b.w, acc[2][3]);
            acc[3][0] = fmaf(a.w, b.x, acc[3][0]);
            acc[3][1] = fmaf(a.w, b.y, acc[3][1]);
            acc[3][2] = fmaf(a.w, b.z, acc[3][2]);
            acc[3][3] = fmaf(a.w, b.w, acc[3][3]);
        }
        __syncthreads();
    }

#pragma unroll
    for (int j = 0; j < 4; ++j) {
        int grow = row0 + ty * 4 + j;
        if (grow < N_NODES) {
            float dr = dis[grow];
            uint2 p;
            p.x = pack2(acc[j][0] * dr, acc[j][1] * dr);
            p.y = pack2(acc[j][2] * dr, acc[j][3] * dr);
            ((uint2*)g16)[(size_t)grow * 16 + tx] = p;
        }
    }
}

// hout[i,:] = act( dis[i] * (g16[i,:] + sum_e g16[ssrc[e],:]) + b )   (f32 accum)
// One wave per row; 8 edge slots x 8 lanes x 16B, unroll 2, float2 packed adds.
template <bool RELU>
__global__ __launch_bounds__(256) void k_aggr(const unsigned* __restrict__ g16,
                                              const int* __restrict__ off,
                                              const int* __restrict__ ssrc,
                                              const float* __restrict__ dis,
                                              const float* __restrict__ bias,
                                              float* __restrict__ hout) {
    int row = blockIdx.x * 4 + (threadIdx.x >> 6);
    int lane = threadIdx.x & 63;
    int sub = lane >> 3;   // edge slot 0..7
    int li = lane & 7;     // 16B segment of the 128B row
    if (row >= N_NODES) return;
    const uint4* g4 = (const uint4*)g16;   // row = 8 uint4
    float2 acc[4] = {make_float2(0.f, 0.f), make_float2(0.f, 0.f),
                     make_float2(0.f, 0.f), make_float2(0.f, 0.f)};
    int lo = off[row], hi = off[row + 1];
    int e = lo + sub;
    for (; e + 8 < hi; e += 16) {
        unsigned o0 = (unsigned)ssrc[e] * 8u + (unsigned)li;
        unsigned o1 = (unsigned)ssrc[e + 8] * 8u + (unsigned)li;
        uint4 v0 = g4[o0];
        uint4 v1 = g4[o1];
        acc2(acc[0], bf_pair(v0.x)); acc2(acc[0], bf_pair(v1.x));
        acc2(acc[1], bf_pair(v0.y)); acc2(acc[1], bf_pair(v1.y));
        acc2(acc[2], bf_pair(v0.z)); acc2(acc[2], bf_pair(v1.z));
        acc2(acc[3], bf_pair(v0.w)); acc2(acc[3], bf_pair(v1.w));
    }
    if (e < hi) {
        unsigned o = (unsigned)ssrc[e] * 8u + (unsigned)li;
        uint4 v = g4[o];
        acc2(acc[0], bf_pair(v.x));
        acc2(acc[1], bf_pair(v.y));
        acc2(acc[2], bf_pair(v.z));
        acc2(acc[3], bf_pair(v.w));
    }
    // combine the 8 edge slots (lanes differing in bits 3..5 hold same features)
#pragma unroll
    for (int d = 8; d <= 32; d <<= 1) {
#pragma unroll
        for (int j = 0; j < 4; ++j) {
            acc[j].x += __shfl_xor(acc[j].x, d);
            acc[j].y += __shfl_xor(acc[j].y, d);
        }
    }
    if (sub == 0) {
        uint4 sv = g4[(unsigned)row * 8u + (unsigned)li];
        float2 self[4] = {bf_pair(sv.x), bf_pair(sv.y), bf_pair(sv.z), bf_pair(sv.w)};
        float dr = dis[row];
        float4 b0 = ((const float4*)bias)[li * 2];
        float4 b1 = ((const float4*)bias)[li * 2 + 1];
        float bb[8] = {b0.x, b0.y, b0.z, b0.w, b1.x, b1.y, b1.z, b1.w};
        float o[8];
#pragma unroll
        for (int j = 0; j < 4; ++j) {
            o[2 * j]     = dr * (acc[j].x + self[j].x) + bb[2 * j];
            o[2 * j + 1] = dr * (acc[j].y + self[j].y) + bb[2 * j + 1];
        }
        if (RELU) {
#pragma unroll
            for (int j = 0; j < 8; ++j) o[j] = fmaxf(o[j], 0.f);
        }
        float4* hp = (float4*)&hout[(size_t)row * HID + li * 8];
        hp[0] = make_float4(o[0], o[1], o[2], o[3]);
        hp[1] = make_float4(o[4], o[5], o[6], o[7]);
    }
}

// ---------------- pooling + classifier ----------------

__global__ __launch_bounds__(256) void k_pool1(const float* __restrict__ h,
                                               const int* __restrict__ batch,
                                               float* __restrict__ sums) {
    int lane = threadIdx.x & 63, wv = threadIdx.x >> 6;
    int node0 = blockIdx.x * 256 + wv * 64;
    int node1 = min(node0 + 64, N_NODES);
    float acc = 0.f;
    int cur = -1;
    for (int i = node0; i < node1; ++i) {
        int bi = batch[i];
        if (bi != cur) {
            if (cur >= 0) atomicAdd(&sums[cur * HID + lane], acc);
            acc = 0.f;
            cur = bi;
        }
        acc += h[(size_t)i * HID + lane];
    }
    if (cur >= 0) atomicAdd(&sums[cur * HID + lane], acc);
}

__device__ inline int lower_bound_batch(const int* batch, int key) {
    int lo = 0, hi = N_NODES;
    while (lo < hi) {
        int mid = (lo + hi) >> 1;
        if (batch[mid] < key) lo = mid + 1;
        else hi = mid;
    }
    return lo;
}

__global__ __launch_bounds__(256) void k_cls(const float* __restrict__ sums,
                                             const int* __restrict__ batch,
                                             const float* __restrict__ Wc1,
                                             const float* __restrict__ bc1,
                                             const float* __restrict__ Wc2,
                                             const float* __restrict__ bc2,
                                             float* __restrict__ out) {
    __shared__ float pooled[N_GRAPHS][HID];
    __shared__ float hc[N_GRAPHS][HID / 2];
    __shared__ float cnts[N_GRAPHS];
    int t = threadIdx.x;
    if (t < N_GRAPHS) {
        int lo = lower_bound_batch(batch, t);
        int hi = lower_bound_batch(batch, t + 1);
        cnts[t] = fmaxf((float)(hi - lo), 1.0f);
    }
    __syncthreads();
    for (int idx = t; idx < N_GRAPHS * HID; idx += 256) {
        int gi = idx >> 6;
        pooled[gi][idx & 63] = sums[idx] / cnts[gi];
    }
    __syncthreads();
    for (int idx = t; idx < N_GRAPHS * (HID / 2); idx += 256) {
        int gi = idx >> 5, f = idx & 31;
        float a = bc1[f];
#pragma unroll
        for (int k = 0; k < HID; ++k) a = fmaf(pooled[gi][k], Wc1[k * (HID / 2) + f], a);
        hc[gi][f] = fmaxf(a, 0.f);
    }
    __syncthreads();
    for (int idx = t; idx < N_GRAPHS * OUT_DIM; idx += 256) {
        int gi = idx >> 1, f = idx & 1;
        float a = bc2[f];
#pragma unroll
        for (int k = 0; k < HID / 2; ++k) a = fmaf(hc[gi][k], Wc2[k * OUT_DIM + f], a);
        out[gi * OUT_DIM + f] = a;
    }
}

// ---------------- launch ----------------

extern "C" void kernel_launch(void* const* d_in, const int* in_sizes, int n_in,
                              void* d_out, int out_size, void* d_ws, size_t ws_size,
                              hipStream_t stream) {
    const float* x    = (const float*)d_in[0];
    const int*   eidx = (const int*)d_in[1];
    const int*   batch= (const int*)d_in[2];
    const float* W1 = (const float*)d_in[3];  const float* b1 = (const float*)d_in[4];
    const float* W2 = (const float*)d_in[5];  const float* b2 = (const float*)d_in[6];
    const float* W3 = (const float*)d_in[7];  const float* b3 = (const float*)d_in[8];
    const float* Wc1 = (const float*)d_in[9];  const float* bc1 = (const float*)d_in[10];
    const float* Wc2 = (const float*)d_in[11]; const float* bc2 = (const float*)d_in[12];
    float* out = (float*)d_out;

    const int* esrc = eidx;
    const int* edst = eidx + N_EDGES;

    size_t o = 0;
    auto alloc = [&](size_t bytes) {
        void* p = (char*)d_ws + o;
        o += (bytes + 255) & ~(size_t)255;
        return p;
    };
    int*      bcount  = (int*)alloc((size_t)NB_BUCKETS * 4);
    int*      bbase   = (int*)alloc((size_t)(NB_BUCKETS + 1) * 4);
    float*    dis     = (float*)alloc((size_t)N_NODES * 4);
    unsigned* arena   = (unsigned*)alloc((size_t)NB_BUCKETS * ARENA_CAP * 4);
    int*      ssrc    = (int*)alloc((size_t)N_EDGES * 4);
    int*      off     = (int*)alloc((size_t)(N_NODES + 1) * 4);
    unsigned* g16     = (unsigned*)alloc((size_t)N_NODES * HID * 2);  // bf16 rows
    float*    hbuf    = (float*)alloc((size_t)N_NODES * HID * 4);
    float*    sums    = (float*)alloc((size_t)N_GRAPHS * HID * 4);
    (void)ws_size;

    const int TB = 256;
    int gridG = (N_NODES + 63) / 64;
    int gridR = (N_NODES + 3) / 4;

    // 1) single-pass arena bucketing, then per-bucket CSR finalize
    hipMemsetAsync(bcount, 0, (size_t)NB_BUCKETS * 4, stream);
    hipMemsetAsync(sums, 0, (size_t)N_GRAPHS * HID * 4, stream);
    kb_scatter<<<NCHUNKS, TB, 0, stream>>>(esrc, edst, bcount, arena);
    kb_scan<<<1, 64, 0, stream>>>(bcount, bbase);
    k_bfin<<<NB_BUCKETS, TB, 0, stream>>>(arena, bbase, ssrc, off, dis);

    // 2) conv1
    k_gemm<IN_DIM><<<gridG, TB, 0, stream>>>(x, W1, dis, g16);
    k_aggr<true><<<gridR, TB, 0, stream>>>(g16, off, ssrc, dis, b1, hbuf);

    // 3) conv2
    k_gemm<HID><<<gridG, TB, 0, stream>>>(hbuf, W2, dis, g16);
    k_aggr<true><<<gridR, TB, 0, stream>>>(g16, off, ssrc, dis, b2, hbuf);

    // 4) conv3 (no relu)
    k_gemm<HID><<<gridG, TB, 0, stream>>>(hbuf, W3, dis, g16);
    k_aggr<false><<<gridR, TB, 0, stream>>>(g16, off, ssrc, dis, b3, hbuf);

    // 5) pool + classifier
    k_pool1<<<NB_BUCKETS, TB, 0, stream>>>(hbuf, batch, sums);
    k_cls<<<1, TB, 0, stream>>>(sums, batch, Wc1, bc1, Wc2, bc2, out);
}